// Round 6
// baseline (526.826 us; speedup 1.0000x reference)
//
#include <hip/hip_runtime.h>

typedef unsigned short u16;
typedef short bf16x8 __attribute__((ext_vector_type(8)));
typedef float f32x4 __attribute__((ext_vector_type(4)));

#define B_    128
#define N0_   320
#define C_    512
#define NH_   8
#define HD_   64
#define NTOK  324
#define H_    18
#define AG_   144
#define SCALE 0.125f

typedef __attribute__((address_space(3))) unsigned int as3_u32;
typedef __attribute__((address_space(1))) const unsigned int as1_u32;

__device__ __forceinline__ void gl_lds16(const void* g, void* l) {
  __builtin_amdgcn_global_load_lds((as1_u32*)(unsigned long long)g,
                                   (as3_u32*)(unsigned int)(unsigned long long)l,
                                   16, 0, 0);
}

__device__ __forceinline__ float bfu2f(u16 u) {
  union { unsigned int u; float f; } v; v.u = ((unsigned int)u) << 16; return v.f;
}
__device__ __forceinline__ u16 f2bfu(float f) {
  union { float f; unsigned int u; } v; v.f = f;
  unsigned int r = v.u + 0x7fffu + ((v.u >> 16) & 1u);
  return (u16)(r >> 16);
}

// ---------------------------------------------------------------------------
// x (f32) -> xp (bf16, [B][324][512], pad tokens zero)
// ---------------------------------------------------------------------------
__global__ __launch_bounds__(256) void conv_x(const float* __restrict__ x, u16* __restrict__ xp)
{
  const int idx = blockIdx.x * 256 + threadIdx.x;
  const int row = idx >> 6, c8 = idx & 63;
  const int b = row / NTOK, t = row - b * NTOK;
  u16 o[8];
  if (t < 2 || t >= 322) {
    #pragma unroll
    for (int j = 0; j < 8; ++j) o[j] = 0;
  } else {
    const float* src = x + ((size_t)(b * N0_ + (t - 2))) * C_ + c8 * 8;
    const float4 f0 = *(const float4*)(src);
    const float4 f1 = *(const float4*)(src + 4);
    o[0]=f2bfu(f0.x); o[1]=f2bfu(f0.y); o[2]=f2bfu(f0.z); o[3]=f2bfu(f0.w);
    o[4]=f2bfu(f1.x); o[5]=f2bfu(f1.y); o[6]=f2bfu(f1.z); o[7]=f2bfu(f1.w);
  }
  *(bf16x8*)&xp[(size_t)row * C_ + c8 * 8] = *(bf16x8*)o;
}

// ---------------------------------------------------------------------------
// W (f32, [512][ncols]) -> Wt (bf16, [ncols][512])
// ---------------------------------------------------------------------------
__global__ __launch_bounds__(256) void tconv(const float* __restrict__ W, u16* __restrict__ Wt, int ncols)
{
  __shared__ float T[64][65];
  const int k0 = blockIdx.x * 64, n0 = blockIdx.y * 64;
  const int tid = threadIdx.x;
  const int rr = tid >> 4, cc = tid & 15;
  #pragma unroll
  for (int i = 0; i < 4; ++i) {
    const float4 f = *(const float4*)&W[(size_t)(k0 + i * 16 + rr) * ncols + n0 + cc * 4];
    T[i * 16 + rr][cc * 4 + 0] = f.x; T[i * 16 + rr][cc * 4 + 1] = f.y;
    T[i * 16 + rr][cc * 4 + 2] = f.z; T[i * 16 + rr][cc * 4 + 3] = f.w;
  }
  __syncthreads();
  #pragma unroll
  for (int i = 0; i < 4; ++i) {
    const int n = i * 16 + rr;
    ushort4 u;
    u.x = f2bfu(T[cc * 4 + 0][n]); u.y = f2bfu(T[cc * 4 + 1][n]);
    u.z = f2bfu(T[cc * 4 + 2][n]); u.w = f2bfu(T[cc * 4 + 3][n]);
    *(ushort4*)&Wt[(size_t)(n0 + n) * 512 + k0 + cc * 4] = u;
  }
}

// ---------------------------------------------------------------------------
// MFMA GEMM, 128x128 tile, BK=64. MODE 0: A = xp (row-major 512), out q/k/v.
// MODE 1: A = aob in [bh][t][d] layout (k-chunk CC -> h-block CC>>3, d-chunk
// CC&7), out = d_out f32 + bias.
// ---------------------------------------------------------------------------
template<int MODE>
__global__ __launch_bounds__(256) void mfma_gemm(
    const u16* __restrict__ A, const u16* __restrict__ Bt,
    u16* __restrict__ qb, u16* __restrict__ kb, u16* __restrict__ vb,
    const float* __restrict__ bias, float* __restrict__ outf)
{
  __shared__ __align__(16) u16 As[128 * 64];
  __shared__ __align__(16) u16 Bs[128 * 64];
  const int bx = blockIdx.x;
  const int by = blockIdx.y;
  const int tid = threadIdx.x;
  const int wv = tid >> 6, lane = tid & 63;
  const int lr = lane & 15, lk = lane >> 4;
  const int wr = wv >> 1, wc = wv & 1;
  const int si = lane >> 3, slot = lane & 7;

  size_t arow_src[4];
  #pragma unroll
  for (int jj = 0; jj < 4; ++jj) {
    const int rl = (wv * 4 + jj) * 8 + si;
    const int r = by * 128 + rl;
    if (MODE == 0) {
      arow_src[jj] = (size_t)r * 512;
    } else {
      const int b2 = r / N0_, ii = r - b2 * N0_;
      arow_src[jj] = ((size_t)b2 * 8 * NTOK + (ii + 2)) * 64;   // (b2, h=0, t, d=0)
    }
  }

  f32x4 acc[4][4] = {};
  for (int k0 = 0; k0 < 512; k0 += 64) {
    __syncthreads();
    #pragma unroll
    for (int jj = 0; jj < 4; ++jj) {
      const int rl = (wv * 4 + jj) * 8 + si;
      const int c = slot ^ (rl & 7);
      const u16* asrc = (MODE == 0)
          ? (A + arow_src[jj] + k0 + c * 8)
          : (A + arow_src[jj] + (size_t)(k0 >> 6) * (NTOK * 64) + c * 8);
      gl_lds16(asrc, (char*)As + (wv * 4 + jj) * 1024);
      gl_lds16(Bt + (size_t)(bx * 128 + rl) * 512 + k0 + c * 8,
               (char*)Bs + (wv * 4 + jj) * 1024);
    }
    __syncthreads();
    #pragma unroll
    for (int kk = 0; kk < 2; ++kk) {
      bf16x8 af[4], bf[4];
      #pragma unroll
      for (int m = 0; m < 4; ++m) {
        const int row = wr * 64 + m * 16 + lr;
        af[m] = *(const bf16x8*)((const char*)As + row * 128 + (((kk * 4 + lk) ^ (row & 7)) << 4));
      }
      #pragma unroll
      for (int n = 0; n < 4; ++n) {
        const int row = wc * 64 + n * 16 + lr;
        bf[n] = *(const bf16x8*)((const char*)Bs + row * 128 + (((kk * 4 + lk) ^ (row & 7)) << 4));
      }
      #pragma unroll
      for (int m = 0; m < 4; ++m)
        #pragma unroll
        for (int n = 0; n < 4; ++n)
          acc[m][n] = __builtin_amdgcn_mfma_f32_16x16x32_bf16(af[m], bf[n], acc[m][n], 0, 0, 0);
    }
  }

  if (MODE == 0) {
    const int mat = (bx * 128) >> 9;
    u16* outp = (mat == 0) ? qb : (mat == 1) ? kb : vb;
    #pragma unroll
    for (int m = 0; m < 4; ++m) {
      #pragma unroll
      for (int r = 0; r < 4; ++r) {
        const int row = by * 128 + wr * 64 + m * 16 + lk * 4 + r;
        const int b = row / NTOK, t = row - b * NTOK;
        #pragma unroll
        for (int n = 0; n < 4; ++n) {
          const int col = bx * 128 + wc * 64 + n * 16 + lr;
          const int rem = col & 511, h = rem >> 6, d = rem & 63;
          outp[(((size_t)(b * NH_ + h)) * NTOK + t) * HD_ + d] = f2bfu(acc[m][n][r]);
        }
      }
    }
  } else {
    #pragma unroll
    for (int m = 0; m < 4; ++m) {
      #pragma unroll
      for (int r = 0; r < 4; ++r) {
        const int row = by * 128 + wr * 64 + m * 16 + lk * 4 + r;
        #pragma unroll
        for (int n = 0; n < 4; ++n) {
          const int col = bx * 128 + wc * 64 + n * 16 + lr;
          outf[(size_t)row * C_ + col] = acc[m][n][r] + bias[col];
        }
      }
    }
  }
}

// ---------------------------------------------------------------------------
// Bias precompute (unchanged, verified)
// ---------------------------------------------------------------------------
__global__ void bias_kernel(const float* __restrict__ an, const float* __restrict__ na,
                            const float* __restrict__ ah, const float* __restrict__ aw,
                            const float* __restrict__ ha, const float* __restrict__ wa,
                            float* __restrict__ bAN, float* __restrict__ bNA)
{
  const int blk = blockIdx.x;
  const int h = blk / AG_, a = blk - h * AG_;
  const int tid = threadIdx.x;
  if (tid >= NTOK) return;
  const int y = tid / H_, x = tid - y * H_;
  float cy = (y + 0.5f) * (7.0f / 18.0f) - 0.5f; cy = fminf(fmaxf(cy, 0.f), 6.f);
  float cx = (x + 0.5f) * (7.0f / 18.0f) - 0.5f; cx = fminf(fmaxf(cx, 0.f), 6.f);
  const int y0 = (int)floorf(cy); const float ty = cy - y0; const int y1 = min(y0 + 1, 6);
  const int x0 = (int)floorf(cx); const float tx = cx - x0; const int x1 = min(x0 + 1, 6);
  const float w00 = (1.f - ty) * (1.f - tx), w01 = (1.f - ty) * tx;
  const float w10 = ty * (1.f - tx), w11 = ty * tx;
  const float* anp = an + (size_t)blk * 49;
  const float* nap = na + (size_t)blk * 49;
  const float van = w00 * anp[y0*7+x0] + w01 * anp[y0*7+x1] + w10 * anp[y1*7+x0] + w11 * anp[y1*7+x1];
  const float vna = w00 * nap[y0*7+x0] + w01 * nap[y0*7+x1] + w10 * nap[y1*7+x0] + w11 * nap[y1*7+x1];
  bAN[(size_t)blk * NTOK + tid] = van + ah[(size_t)blk * H_ + y] + aw[(size_t)blk * H_ + x];
  bNA[((size_t)h * NTOK + tid) * AG_ + a] =
      vna + ha[((size_t)h * H_ + y) * AG_ + a] + wa[((size_t)h * H_ + x) * AG_ + a];
}

// ---------------------------------------------------------------------------
// Adaptive pool (unchanged, verified)
// ---------------------------------------------------------------------------
__global__ __launch_bounds__(512) void pool_kernel(const u16* __restrict__ qb, u16* __restrict__ agb)
{
  const int blk = blockIdx.x;
  const int b = blk / AG_, a = blk - b * AG_;
  const int o = a / 12, pc = a - o * 12;
  const int y0 = (3 * o) >> 1, x0 = (3 * pc) >> 1;
  const int c = threadIdx.x; const int h = c >> 6, d = c & 63;
  const size_t base = ((size_t)(b * NH_ + h)) * NTOK * HD_ + d;
  const int t00 = (y0 * H_ + x0) * HD_;
  const float v = bfu2f(qb[base + t00]) + bfu2f(qb[base + t00 + HD_])
                + bfu2f(qb[base + t00 + H_ * HD_]) + bfu2f(qb[base + t00 + H_ * HD_ + HD_]);
  agb[((size_t)(b * NH_ + h)) * AG_ * HD_ + a * HD_ + d] = f2bfu(0.25f * v);
}

// ---------------------------------------------------------------------------
// Fused attention per (b,h): stage1 (ag@K^T -> softmax -> @V) -> avT in LDS ->
// stage2 (q@ag^T -> softmax -> @AV) + dwc epilogue from vT.
// aob written in [bh][t][d] layout (block-exclusive slice of the kb alias;
// all kb reads happen before the mid-kernel barriers -> race-free).
// LDS: vT 46080 + avT 21504 + pW 11520 = 77.3 KB.
// ---------------------------------------------------------------------------
__global__ __launch_bounds__(576) void fused_attn(
    const u16* __restrict__ kb, const u16* __restrict__ vb,
    const u16* __restrict__ qb, const u16* __restrict__ agb,
    const float* __restrict__ bAN, const float* __restrict__ bNA,
    const float* __restrict__ dwc_w, const float* __restrict__ dwc_b,
    u16* __restrict__ aob)
{
  __shared__ __align__(16) u16 vT[64 * 360];    // [d][token], stride 360 (180dw, /4 odd)
  __shared__ __align__(16) u16 avT[64 * 168];   // [d][agent], stride 168 (84dw, /4 odd)
  __shared__ __align__(16) u16 pW[9][16][40];   // per-wave P chunk buffer
  const int bh = blockIdx.x, h = bh & 7;
  const int tid = threadIdx.x;
  const int mt = tid >> 6;                      // wave id 0..8
  const int l = tid & 63, lr = l & 15, lk = l >> 4;

  // zero avT pad agent-columns 144..159 (read by stage2 PV chunk ks=4)
  for (int idx = tid; idx < 128; idx += 576)
    *(bf16x8*)&avT[(idx >> 1) * 168 + 144 + (idx & 1) * 8] = (bf16x8){0,0,0,0,0,0,0,0};

  // vT staging: per-lane 8 coalesced scalar reads -> one ds_write_b128
  const u16* vsrc = vb + (size_t)bh * NTOK * HD_;
  for (int idx = tid; idx < 64 * 45; idx += 576) {
    const int d = idx & 63, c = idx >> 6;
    bf16x8 tv;
    #pragma unroll
    for (int j = 0; j < 8; ++j) {
      const int n = c * 8 + j;
      tv[j] = (n < NTOK) ? (short)vsrc[(size_t)n * HD_ + d] : (short)0;
    }
    *(bf16x8*)&vT[d * 360 + c * 8] = tv;
  }

  // ---- stage 1: S = ag @ K^T ----
  const u16* aga = agb + ((size_t)bh * AG_ + mt * 16 + lr) * HD_ + lk * 8;
  const bf16x8 a0 = *(const bf16x8*)(aga);
  const bf16x8 a1 = *(const bf16x8*)(aga + 32);

  f32x4 acc[21];
  const u16* kbase = kb + (size_t)bh * NTOK * HD_ + lk * 8;
  #pragma unroll
  for (int nt = 0; nt < 21; ++nt) {
    const bf16x8 b0 = *(const bf16x8*)(kbase + (size_t)(nt * 16 + lr) * HD_);
    const bf16x8 b1 = *(const bf16x8*)(kbase + (size_t)(nt * 16 + lr) * HD_ + 32);
    f32x4 c = {0.f, 0.f, 0.f, 0.f};
    c = __builtin_amdgcn_mfma_f32_16x16x32_bf16(a0, b0, c, 0, 0, 0);
    c = __builtin_amdgcn_mfma_f32_16x16x32_bf16(a1, b1, c, 0, 0, 0);
    acc[nt] = c;
  }

  const float* bb = bAN + ((size_t)h * AG_ + mt * 16) * NTOK;
  float mx[4] = {-1e30f, -1e30f, -1e30f, -1e30f};
  #pragma unroll
  for (int nt = 0; nt < 21; ++nt) {
    const int col = nt * 16 + lr;
    const bool valid = (nt < 20) || (lr < 4);
    #pragma unroll
    for (int r = 0; r < 4; ++r) {
      float s = -1e30f;
      if (valid) s = acc[nt][r] * SCALE + bb[(lk * 4 + r) * NTOK + col];
      acc[nt][r] = s;
      mx[r] = fmaxf(mx[r], s);
    }
  }
  #pragma unroll
  for (int r = 0; r < 4; ++r) {
    #pragma unroll
    for (int o = 1; o < 16; o <<= 1) mx[r] = fmaxf(mx[r], __shfl_xor(mx[r], o));
  }
  float sm[4] = {0.f, 0.f, 0.f, 0.f};
  #pragma unroll
  for (int nt = 0; nt < 21; ++nt) {
    #pragma unroll
    for (int r = 0; r < 4; ++r) {
      const float e = __expf(acc[nt][r] - mx[r]);
      acc[nt][r] = e;
      sm[r] += e;
    }
  }
  #pragma unroll
  for (int r = 0; r < 4; ++r) {
    #pragma unroll
    for (int o = 1; o < 16; o <<= 1) sm[r] += __shfl_xor(sm[r], o);
    sm[r] = 1.0f / sm[r];
  }

  __syncthreads();   // vT staging complete (all waves) before PV

  // ---- stage 1 PV: chunked through per-wave pW; AV^T -> avT (LDS) ----
  f32x4 ov[4];
  #pragma unroll
  for (int nt2 = 0; nt2 < 4; ++nt2) ov[nt2] = (f32x4){0.f, 0.f, 0.f, 0.f};
  for (int ks = 0; ks < 11; ++ks) {
    #pragma unroll
    for (int half = 0; half < 2; ++half) {
      const int nt = 2 * ks + half;
      #pragma unroll
      for (int r = 0; r < 4; ++r)
        pW[mt][lk * 4 + r][half * 16 + lr] = (nt < 21) ? f2bfu(acc[nt][r] * sm[r]) : (u16)0;
    }
    const bf16x8 pa = *(const bf16x8*)&pW[mt][lr][lk * 8];
    #pragma unroll
    for (int nt2 = 0; nt2 < 4; ++nt2) {
      const bf16x8 vf = *(const bf16x8*)&vT[(nt2 * 16 + lr) * 360 + ks * 32 + lk * 8];
      ov[nt2] = __builtin_amdgcn_mfma_f32_16x16x32_bf16(pa, vf, ov[nt2], 0, 0, 0);
    }
  }
  #pragma unroll
  for (int nt2 = 0; nt2 < 4; ++nt2) {
    ushort4 u;
    u.x = f2bfu(ov[nt2][0]); u.y = f2bfu(ov[nt2][1]);
    u.z = f2bfu(ov[nt2][2]); u.w = f2bfu(ov[nt2][3]);
    *(ushort4*)&avT[(nt2 * 16 + lr) * 168 + mt * 16 + lk * 4] = u;   // b64, bank-balanced
  }

  __syncthreads();   // avT complete

  // ---- stage 2 + dwc epilogue: waves share 21 token m-tiles ----
  u16* aout = aob + (size_t)bh * NTOK * HD_;
  for (int mt2 = mt; mt2 < 21; mt2 += 9) {
    const int arow = min(mt2 * 16 + lr, NTOK - 1);
    const u16* qa = qb + ((size_t)bh * NTOK + arow) * HD_ + lk * 8;
    const bf16x8 qa0 = *(const bf16x8*)(qa);
    const bf16x8 qa1 = *(const bf16x8*)(qa + 32);

    f32x4 acc2[9];
    #pragma unroll
    for (int nt = 0; nt < 9; ++nt) {
      const u16* bp = agb + ((size_t)bh * AG_ + nt * 16 + lr) * HD_ + lk * 8;
      f32x4 c = {0.f, 0.f, 0.f, 0.f};
      c = __builtin_amdgcn_mfma_f32_16x16x32_bf16(qa0, *(const bf16x8*)(bp), c, 0, 0, 0);
      c = __builtin_amdgcn_mfma_f32_16x16x32_bf16(qa1, *(const bf16x8*)(bp + 32), c, 0, 0, 0);
      acc2[nt] = c;
    }

    float mx2[4] = {-1e30f, -1e30f, -1e30f, -1e30f};
    #pragma unroll
    for (int nt = 0; nt < 9; ++nt) {
      #pragma unroll
      for (int r = 0; r < 4; ++r) {
        const int trow = min(mt2 * 16 + lk * 4 + r, NTOK - 1);
        const float s = acc2[nt][r] * SCALE + bNA[((size_t)h * NTOK + trow) * AG_ + nt * 16 + lr];
        acc2[nt][r] = s;
        mx2[r] = fmaxf(mx2[r], s);
      }
    }
    #pragma unroll
    for (int r = 0; r < 4; ++r) {
      #pragma unroll
      for (int o = 1; o < 16; o <<= 1) mx2[r] = fmaxf(mx2[r], __shfl_xor(mx2[r], o));
    }
    float sm2[4] = {0.f, 0.f, 0.f, 0.f};
    #pragma unroll
    for (int nt = 0; nt < 9; ++nt) {
      #pragma unroll
      for (int r = 0; r < 4; ++r) {
        const float e = __expf(acc2[nt][r] - mx2[r]);
        acc2[nt][r] = e;
        sm2[r] += e;
      }
    }
    #pragma unroll
    for (int r = 0; r < 4; ++r) {
      #pragma unroll
      for (int o = 1; o < 16; o <<= 1) sm2[r] += __shfl_xor(sm2[r], o);
      sm2[r] = 1.0f / sm2[r];
    }

    f32x4 ov2[4];
    #pragma unroll
    for (int nt2 = 0; nt2 < 4; ++nt2) ov2[nt2] = (f32x4){0.f, 0.f, 0.f, 0.f};
    for (int ks = 0; ks < 5; ++ks) {
      #pragma unroll
      for (int half = 0; half < 2; ++half) {
        const int nt = 2 * ks + half;
        #pragma unroll
        for (int r = 0; r < 4; ++r)
          pW[mt][lk * 4 + r][half * 16 + lr] = (nt < 9) ? f2bfu(acc2[nt][r] * sm2[r]) : (u16)0;
      }
      const bf16x8 pa = *(const bf16x8*)&pW[mt][lr][lk * 8];
      #pragma unroll
      for (int nt2 = 0; nt2 < 4; ++nt2) {
        const bf16x8 vf = *(const bf16x8*)&avT[(nt2 * 16 + lr) * 168 + ks * 32 + lk * 8];
        ov2[nt2] = __builtin_amdgcn_mfma_f32_16x16x32_bf16(pa, vf, ov2[nt2], 0, 0, 0);
      }
    }

    // epilogue: + depthwise conv from vT; store aob [bh][t][d]
    #pragma unroll
    for (int nt2 = 0; nt2 < 4; ++nt2) {
      const int d = nt2 * 16 + lr;
      const float* wp = dwc_w + (size_t)(h * 64 + d) * 9;
      float w9[9];
      #pragma unroll
      for (int j = 0; j < 9; ++j) w9[j] = wp[j];
      const float cb = dwc_b[h * 64 + d];
      #pragma unroll
      for (int r = 0; r < 4; ++r) {
        const int t = mt2 * 16 + lk * 4 + r;
        if (t < NTOK) {
          const int y = t / H_, x = t - y * H_;
          float conv = cb;
          #pragma unroll
          for (int ky = 0; ky < 3; ++ky) {
            const int yy = y + ky - 1;
            if (yy < 0 || yy >= H_) continue;
            #pragma unroll
            for (int kx = 0; kx < 3; ++kx) {
              const int xc = x + kx - 1;
              if (xc < 0 || xc >= H_) continue;
              conv += w9[ky * 3 + kx] * bfu2f(vT[d * 360 + yy * H_ + xc]);
            }
          }
          aout[(size_t)t * HD_ + d] = f2bfu(ov2[nt2][r] + conv);
        }
      }
    }
  }
}

extern "C" void kernel_launch(void* const* d_in, const int* in_sizes, int n_in,
                              void* d_out, int out_size, void* d_ws, size_t ws_size,
                              hipStream_t stream)
{
  (void)in_sizes; (void)n_in; (void)out_size;
  const float* x      = (const float*)d_in[0];
  const float* qkv_w  = (const float*)d_in[1];
  const float* proj_w = (const float*)d_in[2];
  const float* proj_b = (const float*)d_in[3];
  const float* dwc_w  = (const float*)d_in[4];
  const float* dwc_b  = (const float*)d_in[5];
  const float* an     = (const float*)d_in[6];
  const float* na     = (const float*)d_in[7];
  const float* ah     = (const float*)d_in[8];
  const float* aw     = (const float*)d_in[9];
  const float* ha     = (const float*)d_in[10];
  const float* wa     = (const float*)d_in[11];

  char* ws = (char*)d_ws;
  const size_t QB  = (size_t)B_ * NH_ * NTOK * HD_ * 2;   // 42,467,328 (== xp bytes)
  const size_t AGB = (size_t)B_ * NH_ * AG_  * HD_ * 2;   // 18,874,368
  const size_t BB  = (size_t)NH_ * AG_ * NTOK * 4;        //  1,492,992
  const size_t WQ  = (size_t)1536 * 512 * 2;              //  1,572,864
  const size_t WP  = (size_t)512 * 512 * 2;               //    524,288
  u16* qb    = (u16*)(ws);
  u16* kb    = (u16*)(ws + QB);
  u16* vb    = (u16*)(ws + 2 * QB);
  u16* xp    = (u16*)(ws + 3 * QB);                       // dead after GEMM<0>
  u16* agb   = (u16*)(ws + 3 * QB);                       // overlays xp
  float* bAN = (float*)(ws + 3 * QB + AGB);               // overlays xp
  float* bNA = (float*)(ws + 3 * QB + AGB + BB);          // overlays xp (21.9MB < 42.5MB)
  u16* wqkvT = (u16*)(ws + 4 * QB);
  u16* wprojT= (u16*)(ws + 4 * QB + WQ);
  u16* aob   = kb;                                        // [bh][t][d]; block-exclusive slices
  if (ws_size < 4 * QB + WQ + WP) return;

  conv_x   <<<dim3(B_ * NTOK * 64 / 256), dim3(256), 0, stream>>>(x, xp);
  tconv    <<<dim3(8, 24), dim3(256), 0, stream>>>(qkv_w, wqkvT, 1536);
  tconv    <<<dim3(8, 8),  dim3(256), 0, stream>>>(proj_w, wprojT, 512);
  mfma_gemm<0><<<dim3(12, 324), dim3(256), 0, stream>>>(xp, wqkvT, qb, kb, vb, nullptr, nullptr);
  pool_kernel<<<dim3(B_ * AG_),  dim3(512), 0, stream>>>(qb, agb);
  bias_kernel<<<dim3(NH_ * AG_), dim3(324), 0, stream>>>(an, na, ah, aw, ha, wa, bAN, bNA);
  fused_attn<<<dim3(B_ * NH_), dim3(576), 0, stream>>>(kb, vb, qb, agb, bAN, bNA, dwc_w, dwc_b, aob);
  mfma_gemm<1><<<dim3(4, 320), dim3(256), 0, stream>>>(aob, wprojT, nullptr, nullptr, nullptr, proj_b, (float*)d_out);
}

// Round 7
// 501.954 us; speedup vs baseline: 1.0496x; 1.0496x over previous
//
#include <hip/hip_runtime.h>

typedef unsigned short u16;
typedef short bf16x8 __attribute__((ext_vector_type(8)));
typedef float f32x4 __attribute__((ext_vector_type(4)));

#define B_    128
#define N0_   320
#define C_    512
#define NH_   8
#define HD_   64
#define NTOK  324
#define H_    18
#define AG_   144
#define SCALE 0.125f

typedef __attribute__((address_space(3))) unsigned int as3_u32;
typedef __attribute__((address_space(1))) const unsigned int as1_u32;

__device__ __forceinline__ void gl_lds16(const void* g, void* l) {
  __builtin_amdgcn_global_load_lds((as1_u32*)(unsigned long long)g,
                                   (as3_u32*)(unsigned int)(unsigned long long)l,
                                   16, 0, 0);
}

__device__ __forceinline__ float bfu2f(u16 u) {
  union { unsigned int u; float f; } v; v.u = ((unsigned int)u) << 16; return v.f;
}
__device__ __forceinline__ u16 f2bfu(float f) {
  union { float f; unsigned int u; } v; v.f = f;
  unsigned int r = v.u + 0x7fffu + ((v.u >> 16) & 1u);
  return (u16)(r >> 16);
}

// ---------------------------------------------------------------------------
// x (f32) -> xp (bf16, [B][324][512], pad tokens zero)
// ---------------------------------------------------------------------------
__global__ __launch_bounds__(256) void conv_x(const float* __restrict__ x, u16* __restrict__ xp)
{
  const int idx = blockIdx.x * 256 + threadIdx.x;
  const int row = idx >> 6, c8 = idx & 63;
  const int b = row / NTOK, t = row - b * NTOK;
  u16 o[8];
  if (t < 2 || t >= 322) {
    #pragma unroll
    for (int j = 0; j < 8; ++j) o[j] = 0;
  } else {
    const float* src = x + ((size_t)(b * N0_ + (t - 2))) * C_ + c8 * 8;
    const float4 f0 = *(const float4*)(src);
    const float4 f1 = *(const float4*)(src + 4);
    o[0]=f2bfu(f0.x); o[1]=f2bfu(f0.y); o[2]=f2bfu(f0.z); o[3]=f2bfu(f0.w);
    o[4]=f2bfu(f1.x); o[5]=f2bfu(f1.y); o[6]=f2bfu(f1.z); o[7]=f2bfu(f1.w);
  }
  *(bf16x8*)&xp[(size_t)row * C_ + c8 * 8] = *(bf16x8*)o;
}

// ---------------------------------------------------------------------------
// W (f32, [512][ncols]) -> Wt (bf16, [ncols][512])
// ---------------------------------------------------------------------------
__global__ __launch_bounds__(256) void tconv(const float* __restrict__ W, u16* __restrict__ Wt, int ncols)
{
  __shared__ float T[64][65];
  const int k0 = blockIdx.x * 64, n0 = blockIdx.y * 64;
  const int tid = threadIdx.x;
  const int rr = tid >> 4, cc = tid & 15;
  #pragma unroll
  for (int i = 0; i < 4; ++i) {
    const float4 f = *(const float4*)&W[(size_t)(k0 + i * 16 + rr) * ncols + n0 + cc * 4];
    T[i * 16 + rr][cc * 4 + 0] = f.x; T[i * 16 + rr][cc * 4 + 1] = f.y;
    T[i * 16 + rr][cc * 4 + 2] = f.z; T[i * 16 + rr][cc * 4 + 3] = f.w;
  }
  __syncthreads();
  #pragma unroll
  for (int i = 0; i < 4; ++i) {
    const int n = i * 16 + rr;
    ushort4 u;
    u.x = f2bfu(T[cc * 4 + 0][n]); u.y = f2bfu(T[cc * 4 + 1][n]);
    u.z = f2bfu(T[cc * 4 + 2][n]); u.w = f2bfu(T[cc * 4 + 3][n]);
    *(ushort4*)&Wt[(size_t)(n0 + n) * 512 + k0 + cc * 4] = u;
  }
}

// ---------------------------------------------------------------------------
// MFMA GEMM (unchanged, verified). MODE 0: xp -> q/k/v. MODE 1: aob[bh][t][d]
// gather -> d_out f32 + bias.
// ---------------------------------------------------------------------------
template<int MODE>
__global__ __launch_bounds__(256) void mfma_gemm(
    const u16* __restrict__ A, const u16* __restrict__ Bt,
    u16* __restrict__ qb, u16* __restrict__ kb, u16* __restrict__ vb,
    const float* __restrict__ bias, float* __restrict__ outf)
{
  __shared__ __align__(16) u16 As[128 * 64];
  __shared__ __align__(16) u16 Bs[128 * 64];
  const int bx = blockIdx.x;
  const int by = blockIdx.y;
  const int tid = threadIdx.x;
  const int wv = tid >> 6, lane = tid & 63;
  const int lr = lane & 15, lk = lane >> 4;
  const int wr = wv >> 1, wc = wv & 1;
  const int si = lane >> 3, slot = lane & 7;

  size_t arow_src[4];
  #pragma unroll
  for (int jj = 0; jj < 4; ++jj) {
    const int rl = (wv * 4 + jj) * 8 + si;
    const int r = by * 128 + rl;
    if (MODE == 0) {
      arow_src[jj] = (size_t)r * 512;
    } else {
      const int b2 = r / N0_, ii = r - b2 * N0_;
      arow_src[jj] = ((size_t)b2 * 8 * NTOK + (ii + 2)) * 64;
    }
  }

  f32x4 acc[4][4] = {};
  for (int k0 = 0; k0 < 512; k0 += 64) {
    __syncthreads();
    #pragma unroll
    for (int jj = 0; jj < 4; ++jj) {
      const int rl = (wv * 4 + jj) * 8 + si;
      const int c = slot ^ (rl & 7);
      const u16* asrc = (MODE == 0)
          ? (A + arow_src[jj] + k0 + c * 8)
          : (A + arow_src[jj] + (size_t)(k0 >> 6) * (NTOK * 64) + c * 8);
      gl_lds16(asrc, (char*)As + (wv * 4 + jj) * 1024);
      gl_lds16(Bt + (size_t)(bx * 128 + rl) * 512 + k0 + c * 8,
               (char*)Bs + (wv * 4 + jj) * 1024);
    }
    __syncthreads();
    #pragma unroll
    for (int kk = 0; kk < 2; ++kk) {
      bf16x8 af[4], bf[4];
      #pragma unroll
      for (int m = 0; m < 4; ++m) {
        const int row = wr * 64 + m * 16 + lr;
        af[m] = *(const bf16x8*)((const char*)As + row * 128 + (((kk * 4 + lk) ^ (row & 7)) << 4));
      }
      #pragma unroll
      for (int n = 0; n < 4; ++n) {
        const int row = wc * 64 + n * 16 + lr;
        bf[n] = *(const bf16x8*)((const char*)Bs + row * 128 + (((kk * 4 + lk) ^ (row & 7)) << 4));
      }
      #pragma unroll
      for (int m = 0; m < 4; ++m)
        #pragma unroll
        for (int n = 0; n < 4; ++n)
          acc[m][n] = __builtin_amdgcn_mfma_f32_16x16x32_bf16(af[m], bf[n], acc[m][n], 0, 0, 0);
    }
  }

  if (MODE == 0) {
    const int mat = (bx * 128) >> 9;
    u16* outp = (mat == 0) ? qb : (mat == 1) ? kb : vb;
    #pragma unroll
    for (int m = 0; m < 4; ++m) {
      #pragma unroll
      for (int r = 0; r < 4; ++r) {
        const int row = by * 128 + wr * 64 + m * 16 + lk * 4 + r;
        const int b = row / NTOK, t = row - b * NTOK;
        #pragma unroll
        for (int n = 0; n < 4; ++n) {
          const int col = bx * 128 + wc * 64 + n * 16 + lr;
          const int rem = col & 511, h = rem >> 6, d = rem & 63;
          outp[(((size_t)(b * NH_ + h)) * NTOK + t) * HD_ + d] = f2bfu(acc[m][n][r]);
        }
      }
    }
  } else {
    #pragma unroll
    for (int m = 0; m < 4; ++m) {
      #pragma unroll
      for (int r = 0; r < 4; ++r) {
        const int row = by * 128 + wr * 64 + m * 16 + lk * 4 + r;
        #pragma unroll
        for (int n = 0; n < 4; ++n) {
          const int col = bx * 128 + wc * 64 + n * 16 + lr;
          outf[(size_t)row * C_ + col] = acc[m][n][r] + bias[col];
        }
      }
    }
  }
}

// ---------------------------------------------------------------------------
// Bias precompute -> bf16 outputs (halves fused_attn's dominant fetch stream)
// ---------------------------------------------------------------------------
__global__ void bias_kernel(const float* __restrict__ an, const float* __restrict__ na,
                            const float* __restrict__ ah, const float* __restrict__ aw,
                            const float* __restrict__ ha, const float* __restrict__ wa,
                            u16* __restrict__ bAN, u16* __restrict__ bNA)
{
  const int blk = blockIdx.x;
  const int h = blk / AG_, a = blk - h * AG_;
  const int tid = threadIdx.x;
  if (tid >= NTOK) return;
  const int y = tid / H_, x = tid - y * H_;
  float cy = (y + 0.5f) * (7.0f / 18.0f) - 0.5f; cy = fminf(fmaxf(cy, 0.f), 6.f);
  float cx = (x + 0.5f) * (7.0f / 18.0f) - 0.5f; cx = fminf(fmaxf(cx, 0.f), 6.f);
  const int y0 = (int)floorf(cy); const float ty = cy - y0; const int y1 = min(y0 + 1, 6);
  const int x0 = (int)floorf(cx); const float tx = cx - x0; const int x1 = min(x0 + 1, 6);
  const float w00 = (1.f - ty) * (1.f - tx), w01 = (1.f - ty) * tx;
  const float w10 = ty * (1.f - tx), w11 = ty * tx;
  const float* anp = an + (size_t)blk * 49;
  const float* nap = na + (size_t)blk * 49;
  const float van = w00 * anp[y0*7+x0] + w01 * anp[y0*7+x1] + w10 * anp[y1*7+x0] + w11 * anp[y1*7+x1];
  const float vna = w00 * nap[y0*7+x0] + w01 * nap[y0*7+x1] + w10 * nap[y1*7+x0] + w11 * nap[y1*7+x1];
  bAN[(size_t)blk * NTOK + tid] = f2bfu(van + ah[(size_t)blk * H_ + y] + aw[(size_t)blk * H_ + x]);
  bNA[((size_t)h * NTOK + tid) * AG_ + a] =
      f2bfu(vna + ha[((size_t)h * H_ + y) * AG_ + a] + wa[((size_t)h * H_ + x) * AG_ + a]);
}

// ---------------------------------------------------------------------------
// Adaptive pool (unchanged, verified)
// ---------------------------------------------------------------------------
__global__ __launch_bounds__(512) void pool_kernel(const u16* __restrict__ qb, u16* __restrict__ agb)
{
  const int blk = blockIdx.x;
  const int b = blk / AG_, a = blk - b * AG_;
  const int o = a / 12, pc = a - o * 12;
  const int y0 = (3 * o) >> 1, x0 = (3 * pc) >> 1;
  const int c = threadIdx.x; const int h = c >> 6, d = c & 63;
  const size_t base = ((size_t)(b * NH_ + h)) * NTOK * HD_ + d;
  const int t00 = (y0 * H_ + x0) * HD_;
  const float v = bfu2f(qb[base + t00]) + bfu2f(qb[base + t00 + HD_])
                + bfu2f(qb[base + t00 + H_ * HD_]) + bfu2f(qb[base + t00 + H_ * HD_ + HD_]);
  agb[((size_t)(b * NH_ + h)) * AG_ * HD_ + a * HD_ + d] = f2bfu(0.25f * v);
}

// ---------------------------------------------------------------------------
// Fused attention per (b,h). Changes vs round 6:
//  - stage-2 PV uses SWAPPED mfma (D^T): lane col=token, rows=4 consecutive d
//    -> epilogue = 4x ushort4 coalescing-friendly stores (was 16 scalar u16).
//  - dwc weights/bias staged in LDS (bf16 wL) -> broadcast reads.
//  - biases read as bf16.
//  - s_setprio(1) around MFMA clusters.
// ---------------------------------------------------------------------------
__global__ __launch_bounds__(576) void fused_attn(
    const u16* __restrict__ kb, const u16* __restrict__ vb,
    const u16* __restrict__ qb, const u16* __restrict__ agb,
    const u16* __restrict__ bAN, const u16* __restrict__ bNA,
    const float* __restrict__ dwc_w, const float* __restrict__ dwc_b,
    u16* __restrict__ aob)
{
  __shared__ __align__(16) u16 vT[64 * 360];    // [d][token]
  __shared__ __align__(16) u16 avT[64 * 168];   // [d][agent]
  __shared__ __align__(16) u16 pW[9][16][40];   // per-wave P chunk buffer
  __shared__ u16 wL[64 * 10];                   // dwc w9+bias, bf16
  const int bh = blockIdx.x, h = bh & 7;
  const int tid = threadIdx.x;
  const int mt = tid >> 6;
  const int l = tid & 63, lr = l & 15, lk = l >> 4;

  // dwc weights -> LDS (bf16)
  for (int idx = tid; idx < 640; idx += 576) {
    const int d = idx / 10, j = idx - d * 10;
    wL[idx] = f2bfu((j < 9) ? dwc_w[(size_t)(h * 64 + d) * 9 + j] : dwc_b[h * 64 + d]);
  }
  // zero avT pad agent-columns 144..159
  for (int idx = tid; idx < 128; idx += 576)
    *(bf16x8*)&avT[(idx >> 1) * 168 + 144 + (idx & 1) * 8] = (bf16x8){0,0,0,0,0,0,0,0};

  // vT staging: coalesced global reads, b128 LDS writes
  const u16* vsrc = vb + (size_t)bh * NTOK * HD_;
  for (int idx = tid; idx < 64 * 45; idx += 576) {
    const int d = idx & 63, c = idx >> 6;
    bf16x8 tv;
    #pragma unroll
    for (int j = 0; j < 8; ++j) {
      const int n = c * 8 + j;
      tv[j] = (n < NTOK) ? (short)vsrc[(size_t)n * HD_ + d] : (short)0;
    }
    *(bf16x8*)&vT[d * 360 + c * 8] = tv;
  }

  // ---- stage 1 QK: S = ag @ K^T ----
  const u16* aga = agb + ((size_t)bh * AG_ + mt * 16 + lr) * HD_ + lk * 8;
  const bf16x8 a0 = *(const bf16x8*)(aga);
  const bf16x8 a1 = *(const bf16x8*)(aga + 32);

  f32x4 acc[21];
  const u16* kbase = kb + (size_t)bh * NTOK * HD_ + lk * 8;
  __builtin_amdgcn_s_setprio(1);
  #pragma unroll
  for (int nt = 0; nt < 21; ++nt) {
    const bf16x8 b0 = *(const bf16x8*)(kbase + (size_t)(nt * 16 + lr) * HD_);
    const bf16x8 b1 = *(const bf16x8*)(kbase + (size_t)(nt * 16 + lr) * HD_ + 32);
    f32x4 c = {0.f, 0.f, 0.f, 0.f};
    c = __builtin_amdgcn_mfma_f32_16x16x32_bf16(a0, b0, c, 0, 0, 0);
    c = __builtin_amdgcn_mfma_f32_16x16x32_bf16(a1, b1, c, 0, 0, 0);
    acc[nt] = c;
  }
  __builtin_amdgcn_s_setprio(0);

  const u16* bb = bAN + ((size_t)h * AG_ + mt * 16) * NTOK;
  float mx[4] = {-1e30f, -1e30f, -1e30f, -1e30f};
  #pragma unroll
  for (int nt = 0; nt < 21; ++nt) {
    const int col = nt * 16 + lr;
    const bool valid = (nt < 20) || (lr < 4);
    #pragma unroll
    for (int r = 0; r < 4; ++r) {
      float s = -1e30f;
      if (valid) s = acc[nt][r] * SCALE + bfu2f(bb[(lk * 4 + r) * NTOK + col]);
      acc[nt][r] = s;
      mx[r] = fmaxf(mx[r], s);
    }
  }
  #pragma unroll
  for (int r = 0; r < 4; ++r) {
    #pragma unroll
    for (int o = 1; o < 16; o <<= 1) mx[r] = fmaxf(mx[r], __shfl_xor(mx[r], o));
  }
  float sm[4] = {0.f, 0.f, 0.f, 0.f};
  #pragma unroll
  for (int nt = 0; nt < 21; ++nt) {
    #pragma unroll
    for (int r = 0; r < 4; ++r) {
      const float e = __expf(acc[nt][r] - mx[r]);
      acc[nt][r] = e;
      sm[r] += e;
    }
  }
  #pragma unroll
  for (int r = 0; r < 4; ++r) {
    #pragma unroll
    for (int o = 1; o < 16; o <<= 1) sm[r] += __shfl_xor(sm[r], o);
    sm[r] = 1.0f / sm[r];
  }

  __syncthreads();   // vT staged

  // ---- stage 1 PV: AV^T -> avT (LDS) ----
  f32x4 ov[4];
  #pragma unroll
  for (int nt2 = 0; nt2 < 4; ++nt2) ov[nt2] = (f32x4){0.f, 0.f, 0.f, 0.f};
  for (int ks = 0; ks < 11; ++ks) {
    #pragma unroll
    for (int half = 0; half < 2; ++half) {
      const int nt = 2 * ks + half;
      #pragma unroll
      for (int r = 0; r < 4; ++r)
        pW[mt][lk * 4 + r][half * 16 + lr] = (nt < 21) ? f2bfu(acc[nt][r] * sm[r]) : (u16)0;
    }
    const bf16x8 pa = *(const bf16x8*)&pW[mt][lr][lk * 8];
    __builtin_amdgcn_s_setprio(1);
    #pragma unroll
    for (int nt2 = 0; nt2 < 4; ++nt2) {
      const bf16x8 vf = *(const bf16x8*)&vT[(nt2 * 16 + lr) * 360 + ks * 32 + lk * 8];
      ov[nt2] = __builtin_amdgcn_mfma_f32_16x16x32_bf16(pa, vf, ov[nt2], 0, 0, 0);
    }
    __builtin_amdgcn_s_setprio(0);
  }
  #pragma unroll
  for (int nt2 = 0; nt2 < 4; ++nt2) {
    ushort4 u;
    u.x = f2bfu(ov[nt2][0]); u.y = f2bfu(ov[nt2][1]);
    u.z = f2bfu(ov[nt2][2]); u.w = f2bfu(ov[nt2][3]);
    *(ushort4*)&avT[(nt2 * 16 + lr) * 168 + mt * 16 + lk * 4] = u;
  }

  __syncthreads();   // avT complete

  // ---- stage 2 + dwc epilogue ----
  u16* aout = aob + (size_t)bh * NTOK * HD_;
  for (int mt2 = mt; mt2 < 21; mt2 += 9) {
    const int arow = min(mt2 * 16 + lr, NTOK - 1);
    const u16* qa = qb + ((size_t)bh * NTOK + arow) * HD_ + lk * 8;
    const bf16x8 qa0 = *(const bf16x8*)(qa);
    const bf16x8 qa1 = *(const bf16x8*)(qa + 32);

    f32x4 acc2[9];
    __builtin_amdgcn_s_setprio(1);
    #pragma unroll
    for (int nt = 0; nt < 9; ++nt) {
      const u16* bp = agb + ((size_t)bh * AG_ + nt * 16 + lr) * HD_ + lk * 8;
      f32x4 c = {0.f, 0.f, 0.f, 0.f};
      c = __builtin_amdgcn_mfma_f32_16x16x32_bf16(qa0, *(const bf16x8*)(bp), c, 0, 0, 0);
      c = __builtin_amdgcn_mfma_f32_16x16x32_bf16(qa1, *(const bf16x8*)(bp + 32), c, 0, 0, 0);
      acc2[nt] = c;
    }
    __builtin_amdgcn_s_setprio(0);

    float mx2[4] = {-1e30f, -1e30f, -1e30f, -1e30f};
    #pragma unroll
    for (int nt = 0; nt < 9; ++nt) {
      #pragma unroll
      for (int r = 0; r < 4; ++r) {
        const int trow = min(mt2 * 16 + lk * 4 + r, NTOK - 1);
        const float s = acc2[nt][r] * SCALE + bfu2f(bNA[((size_t)h * NTOK + trow) * AG_ + nt * 16 + lr]);
        acc2[nt][r] = s;
        mx2[r] = fmaxf(mx2[r], s);
      }
    }
    #pragma unroll
    for (int r = 0; r < 4; ++r) {
      #pragma unroll
      for (int o = 1; o < 16; o <<= 1) mx2[r] = fmaxf(mx2[r], __shfl_xor(mx2[r], o));
    }
    float sm2[4] = {0.f, 0.f, 0.f, 0.f};
    #pragma unroll
    for (int nt = 0; nt < 9; ++nt) {
      #pragma unroll
      for (int r = 0; r < 4; ++r) {
        const float e = __expf(acc2[nt][r] - mx2[r]);
        acc2[nt][r] = e;
        sm2[r] += e;
      }
    }
    #pragma unroll
    for (int r = 0; r < 4; ++r) {
      #pragma unroll
      for (int o = 1; o < 16; o <<= 1) sm2[r] += __shfl_xor(sm2[r], o);
      sm2[r] = 1.0f / sm2[r];
    }

    // PV (SWAPPED): D^T[d][t] = mfma(avT-frag, P-frag)
    f32x4 ov2[4];
    #pragma unroll
    for (int dt = 0; dt < 4; ++dt) ov2[dt] = (f32x4){0.f, 0.f, 0.f, 0.f};
    for (int ks = 0; ks < 5; ++ks) {
      #pragma unroll
      for (int half = 0; half < 2; ++half) {
        const int nt = 2 * ks + half;
        #pragma unroll
        for (int r = 0; r < 4; ++r)
          pW[mt][lk * 4 + r][half * 16 + lr] = (nt < 9) ? f2bfu(acc2[nt][r] * sm2[r]) : (u16)0;
      }
      const bf16x8 pa = *(const bf16x8*)&pW[mt][lr][lk * 8];
      __builtin_amdgcn_s_setprio(1);
      #pragma unroll
      for (int dt = 0; dt < 4; ++dt) {
        const bf16x8 vf = *(const bf16x8*)&avT[(dt * 16 + lr) * 168 + ks * 32 + lk * 8];
        ov2[dt] = __builtin_amdgcn_mfma_f32_16x16x32_bf16(vf, pa, ov2[dt], 0, 0, 0);
      }
      __builtin_amdgcn_s_setprio(0);
    }

    // epilogue: lane owns token t = mt2*16+lr, d = dt*16 + lk*4 + r
    const int t = mt2 * 16 + lr;
    if (t < NTOK) {
      const int y = t / H_, x = t - y * H_;
      #pragma unroll
      for (int dt = 0; dt < 4; ++dt) {
        ushort4 u;
        #pragma unroll
        for (int r = 0; r < 4; ++r) {
          const int d = dt * 16 + lk * 4 + r;
          float conv = bfu2f(wL[d * 10 + 9]);
          #pragma unroll
          for (int ky = 0; ky < 3; ++ky) {
            const int yy = y + ky - 1;
            if (yy < 0 || yy >= H_) continue;
            #pragma unroll
            for (int kx = 0; kx < 3; ++kx) {
              const int xc = x + kx - 1;
              if (xc < 0 || xc >= H_) continue;
              conv += bfu2f(wL[d * 10 + ky * 3 + kx]) * bfu2f(vT[d * 360 + yy * H_ + xc]);
            }
          }
          ((u16*)&u)[r] = f2bfu(ov2[dt][r] + conv);
        }
        *(ushort4*)&aout[(size_t)t * HD_ + dt * 16 + lk * 4] = u;
      }
    }
  }
}

extern "C" void kernel_launch(void* const* d_in, const int* in_sizes, int n_in,
                              void* d_out, int out_size, void* d_ws, size_t ws_size,
                              hipStream_t stream)
{
  (void)in_sizes; (void)n_in; (void)out_size;
  const float* x      = (const float*)d_in[0];
  const float* qkv_w  = (const float*)d_in[1];
  const float* proj_w = (const float*)d_in[2];
  const float* proj_b = (const float*)d_in[3];
  const float* dwc_w  = (const float*)d_in[4];
  const float* dwc_b  = (const float*)d_in[5];
  const float* an     = (const float*)d_in[6];
  const float* na     = (const float*)d_in[7];
  const float* ah     = (const float*)d_in[8];
  const float* aw     = (const float*)d_in[9];
  const float* ha     = (const float*)d_in[10];
  const float* wa     = (const float*)d_in[11];

  char* ws = (char*)d_ws;
  const size_t QB  = (size_t)B_ * NH_ * NTOK * HD_ * 2;   // 42,467,328 (== xp bytes)
  const size_t AGB = (size_t)B_ * NH_ * AG_  * HD_ * 2;   // 18,874,368
  const size_t BB  = (size_t)NH_ * AG_ * NTOK * 2;        //    746,496 (bf16 now)
  const size_t WQ  = (size_t)1536 * 512 * 2;              //  1,572,864
  const size_t WP  = (size_t)512 * 512 * 2;               //    524,288
  u16* qb    = (u16*)(ws);
  u16* kb    = (u16*)(ws + QB);
  u16* vb    = (u16*)(ws + 2 * QB);
  u16* xp    = (u16*)(ws + 3 * QB);                       // dead after GEMM<0>
  u16* agb   = (u16*)(ws + 3 * QB);                       // overlays xp
  u16* bAN   = (u16*)(ws + 3 * QB + AGB);                 // overlays xp
  u16* bNA   = (u16*)(ws + 3 * QB + AGB + BB);            // overlays xp
  u16* wqkvT = (u16*)(ws + 4 * QB);
  u16* wprojT= (u16*)(ws + 4 * QB + WQ);
  u16* aob   = kb;                                        // [bh][t][d]; block-exclusive
  if (ws_size < 4 * QB + WQ + WP) return;

  conv_x   <<<dim3(B_ * NTOK * 64 / 256), dim3(256), 0, stream>>>(x, xp);
  tconv    <<<dim3(8, 24), dim3(256), 0, stream>>>(qkv_w, wqkvT, 1536);
  tconv    <<<dim3(8, 8),  dim3(256), 0, stream>>>(proj_w, wprojT, 512);
  mfma_gemm<0><<<dim3(12, 324), dim3(256), 0, stream>>>(xp, wqkvT, qb, kb, vb, nullptr, nullptr);
  pool_kernel<<<dim3(B_ * AG_),  dim3(512), 0, stream>>>(qb, agb);
  bias_kernel<<<dim3(NH_ * AG_), dim3(324), 0, stream>>>(an, na, ah, aw, ha, wa, bAN, bNA);
  fused_attn<<<dim3(B_ * NH_), dim3(576), 0, stream>>>(kb, vb, qb, agb, bAN, bNA, dwc_w, dwc_b, aob);
  mfma_gemm<1><<<dim3(4, 320), dim3(256), 0, stream>>>(aob, wprojT, nullptr, nullptr, nullptr, proj_b, (float*)d_out);
}

// Round 8
// 497.684 us; speedup vs baseline: 1.0586x; 1.0086x over previous
//
#include <hip/hip_runtime.h>

typedef unsigned short u16;
typedef short bf16x8 __attribute__((ext_vector_type(8)));
typedef float f32x4 __attribute__((ext_vector_type(4)));

#define B_    128
#define N0_   320
#define C_    512
#define NH_   8
#define HD_   64
#define NTOK  324
#define H_    18
#define AG_   144
#define SCALE 0.125f

typedef __attribute__((address_space(3))) unsigned int as3_u32;
typedef __attribute__((address_space(1))) const unsigned int as1_u32;

__device__ __forceinline__ void gl_lds16(const void* g, void* l) {
  __builtin_amdgcn_global_load_lds((as1_u32*)(unsigned long long)g,
                                   (as3_u32*)(unsigned int)(unsigned long long)l,
                                   16, 0, 0);
}

__device__ __forceinline__ float bfu2f(u16 u) {
  union { unsigned int u; float f; } v; v.u = ((unsigned int)u) << 16; return v.f;
}
__device__ __forceinline__ u16 f2bfu(float f) {
  union { float f; unsigned int u; } v; v.f = f;
  unsigned int r = v.u + 0x7fffu + ((v.u >> 16) & 1u);
  return (u16)(r >> 16);
}

// ---------------------------------------------------------------------------
// x (f32) -> xp (bf16, [B][324][512], pad tokens zero)
// ---------------------------------------------------------------------------
__global__ __launch_bounds__(256) void conv_x(const float* __restrict__ x, u16* __restrict__ xp)
{
  const int idx = blockIdx.x * 256 + threadIdx.x;
  const int row = idx >> 6, c8 = idx & 63;
  const int b = row / NTOK, t = row - b * NTOK;
  u16 o[8];
  if (t < 2 || t >= 322) {
    #pragma unroll
    for (int j = 0; j < 8; ++j) o[j] = 0;
  } else {
    const float* src = x + ((size_t)(b * N0_ + (t - 2))) * C_ + c8 * 8;
    const float4 f0 = *(const float4*)(src);
    const float4 f1 = *(const float4*)(src + 4);
    o[0]=f2bfu(f0.x); o[1]=f2bfu(f0.y); o[2]=f2bfu(f0.z); o[3]=f2bfu(f0.w);
    o[4]=f2bfu(f1.x); o[5]=f2bfu(f1.y); o[6]=f2bfu(f1.z); o[7]=f2bfu(f1.w);
  }
  *(bf16x8*)&xp[(size_t)row * C_ + c8 * 8] = *(bf16x8*)o;
}

// ---------------------------------------------------------------------------
// W (f32, [512][ncols]) -> Wt (bf16, [ncols][512])
// ---------------------------------------------------------------------------
__global__ __launch_bounds__(256) void tconv(const float* __restrict__ W, u16* __restrict__ Wt, int ncols)
{
  __shared__ float T[64][65];
  const int k0 = blockIdx.x * 64, n0 = blockIdx.y * 64;
  const int tid = threadIdx.x;
  const int rr = tid >> 4, cc = tid & 15;
  #pragma unroll
  for (int i = 0; i < 4; ++i) {
    const float4 f = *(const float4*)&W[(size_t)(k0 + i * 16 + rr) * ncols + n0 + cc * 4];
    T[i * 16 + rr][cc * 4 + 0] = f.x; T[i * 16 + rr][cc * 4 + 1] = f.y;
    T[i * 16 + rr][cc * 4 + 2] = f.z; T[i * 16 + rr][cc * 4 + 3] = f.w;
  }
  __syncthreads();
  #pragma unroll
  for (int i = 0; i < 4; ++i) {
    const int n = i * 16 + rr;
    ushort4 u;
    u.x = f2bfu(T[cc * 4 + 0][n]); u.y = f2bfu(T[cc * 4 + 1][n]);
    u.z = f2bfu(T[cc * 4 + 2][n]); u.w = f2bfu(T[cc * 4 + 3][n]);
    *(ushort4*)&Wt[(size_t)(n0 + n) * 512 + k0 + cc * 4] = u;
  }
}

// ---------------------------------------------------------------------------
// MFMA GEMM (unchanged, verified). MODE 0: xp -> q/k/v. MODE 1: aob[bh][t][d]
// gather -> d_out f32 + bias.
// ---------------------------------------------------------------------------
template<int MODE>
__global__ __launch_bounds__(256) void mfma_gemm(
    const u16* __restrict__ A, const u16* __restrict__ Bt,
    u16* __restrict__ qb, u16* __restrict__ kb, u16* __restrict__ vb,
    const float* __restrict__ bias, float* __restrict__ outf)
{
  __shared__ __align__(16) u16 As[128 * 64];
  __shared__ __align__(16) u16 Bs[128 * 64];
  const int bx = blockIdx.x;
  const int by = blockIdx.y;
  const int tid = threadIdx.x;
  const int wv = tid >> 6, lane = tid & 63;
  const int lr = lane & 15, lk = lane >> 4;
  const int wr = wv >> 1, wc = wv & 1;
  const int si = lane >> 3, slot = lane & 7;

  size_t arow_src[4];
  #pragma unroll
  for (int jj = 0; jj < 4; ++jj) {
    const int rl = (wv * 4 + jj) * 8 + si;
    const int r = by * 128 + rl;
    if (MODE == 0) {
      arow_src[jj] = (size_t)r * 512;
    } else {
      const int b2 = r / N0_, ii = r - b2 * N0_;
      arow_src[jj] = ((size_t)b2 * 8 * NTOK + (ii + 2)) * 64;
    }
  }

  f32x4 acc[4][4] = {};
  for (int k0 = 0; k0 < 512; k0 += 64) {
    __syncthreads();
    #pragma unroll
    for (int jj = 0; jj < 4; ++jj) {
      const int rl = (wv * 4 + jj) * 8 + si;
      const int c = slot ^ (rl & 7);
      const u16* asrc = (MODE == 0)
          ? (A + arow_src[jj] + k0 + c * 8)
          : (A + arow_src[jj] + (size_t)(k0 >> 6) * (NTOK * 64) + c * 8);
      gl_lds16(asrc, (char*)As + (wv * 4 + jj) * 1024);
      gl_lds16(Bt + (size_t)(bx * 128 + rl) * 512 + k0 + c * 8,
               (char*)Bs + (wv * 4 + jj) * 1024);
    }
    __syncthreads();
    #pragma unroll
    for (int kk = 0; kk < 2; ++kk) {
      bf16x8 af[4], bf[4];
      #pragma unroll
      for (int m = 0; m < 4; ++m) {
        const int row = wr * 64 + m * 16 + lr;
        af[m] = *(const bf16x8*)((const char*)As + row * 128 + (((kk * 4 + lk) ^ (row & 7)) << 4));
      }
      #pragma unroll
      for (int n = 0; n < 4; ++n) {
        const int row = wc * 64 + n * 16 + lr;
        bf[n] = *(const bf16x8*)((const char*)Bs + row * 128 + (((kk * 4 + lk) ^ (row & 7)) << 4));
      }
      #pragma unroll
      for (int m = 0; m < 4; ++m)
        #pragma unroll
        for (int n = 0; n < 4; ++n)
          acc[m][n] = __builtin_amdgcn_mfma_f32_16x16x32_bf16(af[m], bf[n], acc[m][n], 0, 0, 0);
    }
  }

  if (MODE == 0) {
    const int mat = (bx * 128) >> 9;
    u16* outp = (mat == 0) ? qb : (mat == 1) ? kb : vb;
    #pragma unroll
    for (int m = 0; m < 4; ++m) {
      #pragma unroll
      for (int r = 0; r < 4; ++r) {
        const int row = by * 128 + wr * 64 + m * 16 + lk * 4 + r;
        const int b = row / NTOK, t = row - b * NTOK;
        #pragma unroll
        for (int n = 0; n < 4; ++n) {
          const int col = bx * 128 + wc * 64 + n * 16 + lr;
          const int rem = col & 511, h = rem >> 6, d = rem & 63;
          outp[(((size_t)(b * NH_ + h)) * NTOK + t) * HD_ + d] = f2bfu(acc[m][n][r]);
        }
      }
    }
  } else {
    #pragma unroll
    for (int m = 0; m < 4; ++m) {
      #pragma unroll
      for (int r = 0; r < 4; ++r) {
        const int row = by * 128 + wr * 64 + m * 16 + lk * 4 + r;
        #pragma unroll
        for (int n = 0; n < 4; ++n) {
          const int col = bx * 128 + wc * 64 + n * 16 + lr;
          outf[(size_t)row * C_ + col] = acc[m][n][r] + bias[col];
        }
      }
    }
  }
}

// ---------------------------------------------------------------------------
// Bias precompute -> bf16, TRANSPOSED layouts for b64 fragment loads:
//   bANT[h][t][a]  (stage1: lane loads ushort4 over a=lk*4..+3)
//   bNAT[h][a][t]  (stage2: lane loads ushort4 over t=lk*4..+3)
// ---------------------------------------------------------------------------
__global__ void bias_kernel(const float* __restrict__ an, const float* __restrict__ na,
                            const float* __restrict__ ah, const float* __restrict__ aw,
                            const float* __restrict__ ha, const float* __restrict__ wa,
                            u16* __restrict__ bANT, u16* __restrict__ bNAT)
{
  const int blk = blockIdx.x;
  const int h = blk / AG_, a = blk - h * AG_;
  const int tid = threadIdx.x;
  if (tid >= NTOK) return;
  const int y = tid / H_, x = tid - y * H_;
  float cy = (y + 0.5f) * (7.0f / 18.0f) - 0.5f; cy = fminf(fmaxf(cy, 0.f), 6.f);
  float cx = (x + 0.5f) * (7.0f / 18.0f) - 0.5f; cx = fminf(fmaxf(cx, 0.f), 6.f);
  const int y0 = (int)floorf(cy); const float ty = cy - y0; const int y1 = min(y0 + 1, 6);
  const int x0 = (int)floorf(cx); const float tx = cx - x0; const int x1 = min(x0 + 1, 6);
  const float w00 = (1.f - ty) * (1.f - tx), w01 = (1.f - ty) * tx;
  const float w10 = ty * (1.f - tx), w11 = ty * tx;
  const float* anp = an + (size_t)blk * 49;
  const float* nap = na + (size_t)blk * 49;
  const float van = w00 * anp[y0*7+x0] + w01 * anp[y0*7+x1] + w10 * anp[y1*7+x0] + w11 * anp[y1*7+x1];
  const float vna = w00 * nap[y0*7+x0] + w01 * nap[y0*7+x1] + w10 * nap[y1*7+x0] + w11 * nap[y1*7+x1];
  bANT[((size_t)h * NTOK + tid) * AG_ + a] =
      f2bfu(van + ah[(size_t)blk * H_ + y] + aw[(size_t)blk * H_ + x]);
  bNAT[((size_t)h * AG_ + a) * NTOK + tid] =
      f2bfu(vna + ha[((size_t)h * H_ + y) * AG_ + a] + wa[((size_t)h * H_ + x) * AG_ + a]);
}

// ---------------------------------------------------------------------------
// Adaptive pool (unchanged, verified)
// ---------------------------------------------------------------------------
__global__ __launch_bounds__(512) void pool_kernel(const u16* __restrict__ qb, u16* __restrict__ agb)
{
  const int blk = blockIdx.x;
  const int b = blk / AG_, a = blk - b * AG_;
  const int o = a / 12, pc = a - o * 12;
  const int y0 = (3 * o) >> 1, x0 = (3 * pc) >> 1;
  const int c = threadIdx.x; const int h = c >> 6, d = c & 63;
  const size_t base = ((size_t)(b * NH_ + h)) * NTOK * HD_ + d;
  const int t00 = (y0 * H_ + x0) * HD_;
  const float v = bfu2f(qb[base + t00]) + bfu2f(qb[base + t00 + HD_])
                + bfu2f(qb[base + t00 + H_ * HD_]) + bfu2f(qb[base + t00 + H_ * HD_ + HD_]);
  agb[((size_t)(b * NH_ + h)) * AG_ * HD_ + a * HD_ + d] = f2bfu(0.25f * v);
}

// ---------------------------------------------------------------------------
// Depthwise 3x3 conv: aob[bh][t][d] = dwc(v). Coalesced; runs AFTER stage1
// (aob aliases kb) and BEFORE stage2 (which RMW-adds attention).
// ---------------------------------------------------------------------------
__global__ __launch_bounds__(512) void dwc_kernel(
    const u16* __restrict__ vb, const float* __restrict__ dwc_w,
    const float* __restrict__ dwc_b, u16* __restrict__ aob)
{
  __shared__ __align__(16) u16 vL[NTOK * 64];
  const int hb = blockIdx.x, h = hb >> 7, b = hb & 127;
  const int bh = b * NH_ + h;
  const int tid = threadIdx.x;
  const bf16x8* vs = (const bf16x8*)(vb + (size_t)bh * NTOK * HD_);
  for (int idx = tid; idx < NTOK * 8; idx += 512)
    ((bf16x8*)vL)[idx] = vs[idx];
  const int d = tid & 63, tg = tid >> 6;
  float w9[9];
  #pragma unroll
  for (int j = 0; j < 9; ++j) w9[j] = dwc_w[(size_t)(h * 64 + d) * 9 + j];
  const float cb = dwc_b[h * 64 + d];
  __syncthreads();
  u16* aout = aob + (size_t)bh * NTOK * HD_;
  for (int t = tg; t < NTOK; t += 8) {
    const int y = t / H_, x = t - y * H_;
    float conv = cb;
    #pragma unroll
    for (int ky = 0; ky < 3; ++ky) {
      const int yy = y + ky - 1;
      if (yy < 0 || yy >= H_) continue;
      #pragma unroll
      for (int kx = 0; kx < 3; ++kx) {
        const int xc = x + kx - 1;
        if (xc < 0 || xc >= H_) continue;
        conv += w9[ky * 3 + kx] * bfu2f(vL[(yy * H_ + xc) * 64 + d]);
      }
    }
    aout[(size_t)t * HD_ + d] = f2bfu(conv);
  }
}

// ---------------------------------------------------------------------------
// Stage 1: S=ag@K^T + bANT (b64 bias loads), reg softmax, chunked PV via pW,
// AV^T -> LDS bounce (reuses dead vT region) -> coalesced global avbT[bh][d][a160].
// ---------------------------------------------------------------------------
__global__ __launch_bounds__(576) void stage1_k(
    const u16* __restrict__ kb, const u16* __restrict__ vb,
    const u16* __restrict__ agb, const u16* __restrict__ bANT,
    u16* __restrict__ avbT)
{
  __shared__ __align__(16) u16 vT[64 * 360];
  __shared__ __align__(16) u16 pW[9][16][40];
  const int hb = blockIdx.x, h = hb >> 7, b = hb & 127;
  const int bh = b * NH_ + h;
  const int tid = threadIdx.x;
  const int mt = tid >> 6, l = tid & 63, lr = l & 15, lk = l >> 4;

  // vT staging
  const u16* vsrc = vb + (size_t)bh * NTOK * HD_;
  for (int idx = tid; idx < 64 * 45; idx += 576) {
    const int d = idx & 63, c = idx >> 6;
    bf16x8 tv;
    #pragma unroll
    for (int j = 0; j < 8; ++j) {
      const int n = c * 8 + j;
      tv[j] = (n < NTOK) ? (short)vsrc[(size_t)n * HD_ + d] : (short)0;
    }
    *(bf16x8*)&vT[d * 360 + c * 8] = tv;
  }

  // QK
  const u16* aga = agb + ((size_t)bh * AG_ + mt * 16 + lr) * HD_ + lk * 8;
  const bf16x8 a0 = *(const bf16x8*)(aga);
  const bf16x8 a1 = *(const bf16x8*)(aga + 32);

  f32x4 acc[21];
  const u16* kbase = kb + (size_t)bh * NTOK * HD_ + lk * 8;
  __builtin_amdgcn_s_setprio(1);
  #pragma unroll
  for (int nt = 0; nt < 21; ++nt) {
    const bf16x8 b0 = *(const bf16x8*)(kbase + (size_t)(nt * 16 + lr) * HD_);
    const bf16x8 b1 = *(const bf16x8*)(kbase + (size_t)(nt * 16 + lr) * HD_ + 32);
    f32x4 c = {0.f, 0.f, 0.f, 0.f};
    c = __builtin_amdgcn_mfma_f32_16x16x32_bf16(a0, b0, c, 0, 0, 0);
    c = __builtin_amdgcn_mfma_f32_16x16x32_bf16(a1, b1, c, 0, 0, 0);
    acc[nt] = c;
  }
  __builtin_amdgcn_s_setprio(0);

  // bias (ushort4 per nt: a = mt*16+lk*4..+3 at token nt*16+lr) + softmax
  float mx[4] = {-1e30f, -1e30f, -1e30f, -1e30f};
  #pragma unroll
  for (int nt = 0; nt < 21; ++nt) {
    const int t = nt * 16 + lr;
    const bool valid = (nt < 20) || (lr < 4);
    ushort4 b4 = make_ushort4(0, 0, 0, 0);
    if (valid)
      b4 = *(const ushort4*)&bANT[((size_t)h * NTOK + t) * AG_ + mt * 16 + lk * 4];
    #pragma unroll
    for (int r = 0; r < 4; ++r) {
      float s = -1e30f;
      if (valid) s = acc[nt][r] * SCALE + bfu2f(((const u16*)&b4)[r]);
      acc[nt][r] = s;
      mx[r] = fmaxf(mx[r], s);
    }
  }
  #pragma unroll
  for (int r = 0; r < 4; ++r) {
    #pragma unroll
    for (int o = 1; o < 16; o <<= 1) mx[r] = fmaxf(mx[r], __shfl_xor(mx[r], o));
  }
  float sm[4] = {0.f, 0.f, 0.f, 0.f};
  #pragma unroll
  for (int nt = 0; nt < 21; ++nt) {
    #pragma unroll
    for (int r = 0; r < 4; ++r) {
      const float e = __expf(acc[nt][r] - mx[r]);
      acc[nt][r] = e;
      sm[r] += e;
    }
  }
  #pragma unroll
  for (int r = 0; r < 4; ++r) {
    #pragma unroll
    for (int o = 1; o < 16; o <<= 1) sm[r] += __shfl_xor(sm[r], o);
    sm[r] = 1.0f / sm[r];
  }

  __syncthreads();   // vT staged

  // PV chunked: D[a][d], col=lr -> d
  f32x4 ov[4];
  #pragma unroll
  for (int nt2 = 0; nt2 < 4; ++nt2) ov[nt2] = (f32x4){0.f, 0.f, 0.f, 0.f};
  for (int ks = 0; ks < 11; ++ks) {
    #pragma unroll
    for (int half = 0; half < 2; ++half) {
      const int nt = 2 * ks + half;
      #pragma unroll
      for (int r = 0; r < 4; ++r)
        pW[mt][lk * 4 + r][half * 16 + lr] = (nt < 21) ? f2bfu(acc[nt][r] * sm[r]) : (u16)0;
    }
    const bf16x8 pa = *(const bf16x8*)&pW[mt][lr][lk * 8];
    __builtin_amdgcn_s_setprio(1);
    #pragma unroll
    for (int nt2 = 0; nt2 < 4; ++nt2) {
      const bf16x8 vf = *(const bf16x8*)&vT[(nt2 * 16 + lr) * 360 + ks * 32 + lk * 8];
      ov[nt2] = __builtin_amdgcn_mfma_f32_16x16x32_bf16(pa, vf, ov[nt2], 0, 0, 0);
    }
    __builtin_amdgcn_s_setprio(0);
  }

  __syncthreads();   // all PV reads of vT done; safe to overwrite as avT

  u16* avTL = vT;    // [64][168] region inside dead vT
  #pragma unroll
  for (int nt2 = 0; nt2 < 4; ++nt2) {
    ushort4 u;
    u.x = f2bfu(ov[nt2][0]); u.y = f2bfu(ov[nt2][1]);
    u.z = f2bfu(ov[nt2][2]); u.w = f2bfu(ov[nt2][3]);
    *(ushort4*)&avTL[(nt2 * 16 + lr) * 168 + mt * 16 + lk * 4] = u;
  }
  for (int idx = tid; idx < 128; idx += 576)   // zero pad agents 144..159
    *(bf16x8*)&avTL[(idx >> 1) * 168 + 144 + (idx & 1) * 8] = (bf16x8){0,0,0,0,0,0,0,0};

  __syncthreads();   // avT complete

  // coalesced copy LDS -> global avbT[bh][d][a160]
  u16* dst = avbT + (size_t)bh * 64 * 160;
  for (int idx = tid; idx < 64 * 20; idx += 576) {
    const int d = idx / 20, c = idx - d * 20;
    *(bf16x8*)&dst[d * 160 + c * 8] = *(const bf16x8*)&avTL[d * 168 + c * 8];
  }
}

// ---------------------------------------------------------------------------
// Stage 2: S2=q@ag^T + bNAT (b64 bias loads), reg softmax, chunked SWAPPED PV
// (D^T: lane=token, 4 consecutive d) vs LDS-staged avT; RMW onto dwc output.
// Low LDS (31.7KB) + launch_bounds(512,6) -> ~3 blocks/CU.
// ---------------------------------------------------------------------------
__global__ __launch_bounds__(512, 6) void stage2_k(
    const u16* __restrict__ qb, const u16* __restrict__ agb,
    const u16* __restrict__ avbT, const u16* __restrict__ bNAT,
    u16* __restrict__ aob)
{
  __shared__ __align__(16) u16 avT[64 * 168];
  __shared__ __align__(16) u16 pW[8][16][40];
  const int hb = blockIdx.x, h = hb >> 7, b = hb & 127;
  const int bh = b * NH_ + h;
  const int tid = threadIdx.x;
  const int wv = tid >> 6, l = tid & 63, lr = l & 15, lk = l >> 4;

  // stage avT from global (linear b128 copy, 160 -> 168 stride)
  const u16* src = avbT + (size_t)bh * 64 * 160;
  for (int idx = tid; idx < 64 * 20; idx += 512) {
    const int d = idx / 20, c = idx - d * 20;
    *(bf16x8*)&avT[d * 168 + c * 8] = *(const bf16x8*)&src[d * 160 + c * 8];
  }
  __syncthreads();

  u16* aout = aob + (size_t)bh * NTOK * HD_;
  for (int mt2 = wv; mt2 < 21; mt2 += 8) {
    const int arow = min(mt2 * 16 + lr, NTOK - 1);
    const u16* qa = qb + ((size_t)bh * NTOK + arow) * HD_ + lk * 8;
    const bf16x8 qa0 = *(const bf16x8*)(qa);
    const bf16x8 qa1 = *(const bf16x8*)(qa + 32);

    f32x4 acc2[9];
    __builtin_amdgcn_s_setprio(1);
    #pragma unroll
    for (int nt = 0; nt < 9; ++nt) {
      const u16* bp = agb + ((size_t)bh * AG_ + nt * 16 + lr) * HD_ + lk * 8;
      f32x4 c = {0.f, 0.f, 0.f, 0.f};
      c = __builtin_amdgcn_mfma_f32_16x16x32_bf16(qa0, *(const bf16x8*)(bp), c, 0, 0, 0);
      c = __builtin_amdgcn_mfma_f32_16x16x32_bf16(qa1, *(const bf16x8*)(bp + 32), c, 0, 0, 0);
      acc2[nt] = c;
    }
    __builtin_amdgcn_s_setprio(0);

    // bias: ushort4 over t = mt2*16+lk*4..+3 at agent nt*16+lr (bNAT[h][a][t])
    float mx2[4] = {-1e30f, -1e30f, -1e30f, -1e30f};
    const int t0 = mt2 * 16 + lk * 4;
    #pragma unroll
    for (int nt = 0; nt < 9; ++nt) {
      const ushort4 b4 = *(const ushort4*)&bNAT[((size_t)h * AG_ + nt * 16 + lr) * NTOK + t0];
      #pragma unroll
      for (int r = 0; r < 4; ++r) {
        const float s = acc2[nt][r] * SCALE + bfu2f(((const u16*)&b4)[r]);
        acc2[nt][r] = s;
        mx2[r] = fmaxf(mx2[r], s);
      }
    }
    #pragma unroll
    for (int r = 0; r < 4; ++r) {
      #pragma unroll
      for (int o = 1; o < 16; o <<= 1) mx2[r] = fmaxf(mx2[r], __shfl_xor(mx2[r], o));
    }
    float sm2[4] = {0.f, 0.f, 0.f, 0.f};
    #pragma unroll
    for (int nt = 0; nt < 9; ++nt) {
      #pragma unroll
      for (int r = 0; r < 4; ++r) {
        const float e = __expf(acc2[nt][r] - mx2[r]);
        acc2[nt][r] = e;
        sm2[r] += e;
      }
    }
    #pragma unroll
    for (int r = 0; r < 4; ++r) {
      #pragma unroll
      for (int o = 1; o < 16; o <<= 1) sm2[r] += __shfl_xor(sm2[r], o);
      sm2[r] = 1.0f / sm2[r];
    }

    // swapped PV: D^T[d][t]
    f32x4 ov2[4];
    #pragma unroll
    for (int dt = 0; dt < 4; ++dt) ov2[dt] = (f32x4){0.f, 0.f, 0.f, 0.f};
    for (int ks = 0; ks < 5; ++ks) {
      #pragma unroll
      for (int half = 0; half < 2; ++half) {
        const int nt = 2 * ks + half;
        #pragma unroll
        for (int r = 0; r < 4; ++r)
          pW[wv][lk * 4 + r][half * 16 + lr] = (nt < 9) ? f2bfu(acc2[nt][r] * sm2[r]) : (u16)0;
      }
      const bf16x8 pa = *(const bf16x8*)&pW[wv][lr][lk * 8];
      __builtin_amdgcn_s_setprio(1);
      #pragma unroll
      for (int dt = 0; dt < 4; ++dt) {
        const bf16x8 vf = *(const bf16x8*)&avT[(dt * 16 + lr) * 168 + ks * 32 + lk * 8];
        ov2[dt] = __builtin_amdgcn_mfma_f32_16x16x32_bf16(vf, pa, ov2[dt], 0, 0, 0);
      }
      __builtin_amdgcn_s_setprio(0);
    }

    // RMW epilogue onto dwc output: lane owns token t, 4 d per dt
    const int t = mt2 * 16 + lr;
    if (t < NTOK) {
      #pragma unroll
      for (int dt = 0; dt < 4; ++dt) {
        u16* p = &aout[(size_t)t * HD_ + dt * 16 + lk * 4];
        ushort4 u = *(ushort4*)p;
        u.x = f2bfu(bfu2f(u.x) + ov2[dt][0]);
        u.y = f2bfu(bfu2f(u.y) + ov2[dt][1]);
        u.z = f2bfu(bfu2f(u.z) + ov2[dt][2]);
        u.w = f2bfu(bfu2f(u.w) + ov2[dt][3]);
        *(ushort4*)p = u;
      }
    }
  }
}

extern "C" void kernel_launch(void* const* d_in, const int* in_sizes, int n_in,
                              void* d_out, int out_size, void* d_ws, size_t ws_size,
                              hipStream_t stream)
{
  (void)in_sizes; (void)n_in; (void)out_size;
  const float* x      = (const float*)d_in[0];
  const float* qkv_w  = (const float*)d_in[1];
  const float* proj_w = (const float*)d_in[2];
  const float* proj_b = (const float*)d_in[3];
  const float* dwc_w  = (const float*)d_in[4];
  const float* dwc_b  = (const float*)d_in[5];
  const float* an     = (const float*)d_in[6];
  const float* na     = (const float*)d_in[7];
  const float* ah     = (const float*)d_in[8];
  const float* aw     = (const float*)d_in[9];
  const float* ha     = (const float*)d_in[10];
  const float* wa     = (const float*)d_in[11];

  char* ws = (char*)d_ws;
  const size_t QB   = (size_t)B_ * NH_ * NTOK * HD_ * 2;   // 42,467,328 (== xp bytes)
  const size_t AGB  = (size_t)B_ * NH_ * AG_  * HD_ * 2;   // 18,874,368
  const size_t AVTB = (size_t)B_ * NH_ * 64 * 160 * 2;     // 20,971,520
  const size_t BB   = (size_t)NH_ * AG_ * NTOK * 2 + 64;   //    746,560 (bf16 + overread pad)
  const size_t WQ   = (size_t)1536 * 512 * 2;              //  1,572,864
  const size_t WP   = (size_t)512 * 512 * 2;               //    524,288
  u16* qb    = (u16*)(ws);
  u16* kb    = (u16*)(ws + QB);
  u16* vb    = (u16*)(ws + 2 * QB);
  u16* xp    = (u16*)(ws + 3 * QB);                        // dead after GEMM<0>
  u16* agb   = (u16*)(ws + 3 * QB);                        // overlays xp
  u16* avbT  = (u16*)(ws + 3 * QB + AGB);                  // overlays xp
  u16* bANT  = (u16*)(ws + 3 * QB + AGB + AVTB);           // overlays xp tail? 40.6MB<42.5 OK
  u16* wqkvT = (u16*)(ws + 4 * QB);
  u16* wprojT= (u16*)(ws + 4 * QB + WQ);
  u16* bNAT  = (u16*)(ws + 4 * QB + WQ + WP);
  u16* aob   = kb;                                         // [bh][t][d]; block-exclusive
  if (ws_size < 4 * QB + WQ + WP + BB) return;

  conv_x   <<<dim3(B_ * NTOK * 64 / 256), dim3(256), 0, stream>>>(x, xp);
  tconv    <<<dim3(8, 24), dim3(256), 0, stream>>>(qkv_w, wqkvT, 1536);
  tconv    <<<dim3(8, 8),  dim3(256), 0, stream>>>(proj_w, wprojT, 512);
  mfma_gemm<0><<<dim3(12, 324), dim3(256), 0, stream>>>(xp, wqkvT, qb, kb, vb, nullptr, nullptr);
  pool_kernel<<<dim3(B_ * AG_),  dim3(512), 0, stream>>>(qb, agb);
  bias_kernel<<<dim3(NH_ * AG_), dim3(324), 0, stream>>>(an, na, ah, aw, ha, wa, bANT, bNAT);
  stage1_k <<<dim3(NH_ * B_), dim3(576), 0, stream>>>(kb, vb, agb, bANT, avbT);
  dwc_kernel<<<dim3(NH_ * B_), dim3(512), 0, stream>>>(vb, dwc_w, dwc_b, aob);
  stage2_k <<<dim3(NH_ * B_), dim3(512), 0, stream>>>(qb, agb, avbT, bNAT, aob);
  mfma_gemm<1><<<dim3(4, 320), dim3(256), 0, stream>>>(aob, wprojT, nullptr, nullptr, nullptr, proj_b, (float*)d_out);
}

// Round 9
// 487.852 us; speedup vs baseline: 1.0799x; 1.0202x over previous
//
#include <hip/hip_runtime.h>

typedef unsigned short u16;
typedef short bf16x8 __attribute__((ext_vector_type(8)));
typedef float f32x4 __attribute__((ext_vector_type(4)));

#define B_    128
#define N0_   320
#define C_    512
#define NH_   8
#define HD_   64
#define NTOK  324
#define H_    18
#define AG_   144
#define SCALE 0.125f

typedef __attribute__((address_space(3))) unsigned int as3_u32;
typedef __attribute__((address_space(1))) const unsigned int as1_u32;

__device__ __forceinline__ void gl_lds16(const void* g, void* l) {
  __builtin_amdgcn_global_load_lds((as1_u32*)(unsigned long long)g,
                                   (as3_u32*)(unsigned int)(unsigned long long)l,
                                   16, 0, 0);
}

__device__ __forceinline__ float bfu2f(u16 u) {
  union { unsigned int u; float f; } v; v.u = ((unsigned int)u) << 16; return v.f;
}
__device__ __forceinline__ u16 f2bfu(float f) {
  union { float f; unsigned int u; } v; v.f = f;
  unsigned int r = v.u + 0x7fffu + ((v.u >> 16) & 1u);
  return (u16)(r >> 16);
}

// ---------------------------------------------------------------------------
// x (f32) -> xp (bf16, [B][324][512], pad tokens zero)
// ---------------------------------------------------------------------------
__global__ __launch_bounds__(256) void conv_x(const float* __restrict__ x, u16* __restrict__ xp)
{
  const int idx = blockIdx.x * 256 + threadIdx.x;
  const int row = idx >> 6, c8 = idx & 63;
  const int b = row / NTOK, t = row - b * NTOK;
  u16 o[8];
  if (t < 2 || t >= 322) {
    #pragma unroll
    for (int j = 0; j < 8; ++j) o[j] = 0;
  } else {
    const float* src = x + ((size_t)(b * N0_ + (t - 2))) * C_ + c8 * 8;
    const float4 f0 = *(const float4*)(src);
    const float4 f1 = *(const float4*)(src + 4);
    o[0]=f2bfu(f0.x); o[1]=f2bfu(f0.y); o[2]=f2bfu(f0.z); o[3]=f2bfu(f0.w);
    o[4]=f2bfu(f1.x); o[5]=f2bfu(f1.y); o[6]=f2bfu(f1.z); o[7]=f2bfu(f1.w);
  }
  *(bf16x8*)&xp[(size_t)row * C_ + c8 * 8] = *(bf16x8*)o;
}

// ---------------------------------------------------------------------------
// W (f32, [512][ncols]) -> Wt (bf16, [ncols][512])
// ---------------------------------------------------------------------------
__global__ __launch_bounds__(256) void tconv(const float* __restrict__ W, u16* __restrict__ Wt, int ncols)
{
  __shared__ float T[64][65];
  const int k0 = blockIdx.x * 64, n0 = blockIdx.y * 64;
  const int tid = threadIdx.x;
  const int rr = tid >> 4, cc = tid & 15;
  #pragma unroll
  for (int i = 0; i < 4; ++i) {
    const float4 f = *(const float4*)&W[(size_t)(k0 + i * 16 + rr) * ncols + n0 + cc * 4];
    T[i * 16 + rr][cc * 4 + 0] = f.x; T[i * 16 + rr][cc * 4 + 1] = f.y;
    T[i * 16 + rr][cc * 4 + 2] = f.z; T[i * 16 + rr][cc * 4 + 3] = f.w;
  }
  __syncthreads();
  #pragma unroll
  for (int i = 0; i < 4; ++i) {
    const int n = i * 16 + rr;
    ushort4 u;
    u.x = f2bfu(T[cc * 4 + 0][n]); u.y = f2bfu(T[cc * 4 + 1][n]);
    u.z = f2bfu(T[cc * 4 + 2][n]); u.w = f2bfu(T[cc * 4 + 3][n]);
    *(ushort4*)&Wt[(size_t)(n0 + n) * 512 + k0 + cc * 4] = u;
  }
}

// ---------------------------------------------------------------------------
// MFMA GEMM (unchanged, verified). MODE 0: xp -> q/k/v. MODE 1: aob[bh][t][d]
// gather -> d_out f32 + bias.
// ---------------------------------------------------------------------------
template<int MODE>
__global__ __launch_bounds__(256) void mfma_gemm(
    const u16* __restrict__ A, const u16* __restrict__ Bt,
    u16* __restrict__ qb, u16* __restrict__ kb, u16* __restrict__ vb,
    const float* __restrict__ bias, float* __restrict__ outf)
{
  __shared__ __align__(16) u16 As[128 * 64];
  __shared__ __align__(16) u16 Bs[128 * 64];
  const int bx = blockIdx.x;
  const int by = blockIdx.y;
  const int tid = threadIdx.x;
  const int wv = tid >> 6, lane = tid & 63;
  const int lr = lane & 15, lk = lane >> 4;
  const int wr = wv >> 1, wc = wv & 1;
  const int si = lane >> 3, slot = lane & 7;

  size_t arow_src[4];
  #pragma unroll
  for (int jj = 0; jj < 4; ++jj) {
    const int rl = (wv * 4 + jj) * 8 + si;
    const int r = by * 128 + rl;
    if (MODE == 0) {
      arow_src[jj] = (size_t)r * 512;
    } else {
      const int b2 = r / N0_, ii = r - b2 * N0_;
      arow_src[jj] = ((size_t)b2 * 8 * NTOK + (ii + 2)) * 64;
    }
  }

  f32x4 acc[4][4] = {};
  for (int k0 = 0; k0 < 512; k0 += 64) {
    __syncthreads();
    #pragma unroll
    for (int jj = 0; jj < 4; ++jj) {
      const int rl = (wv * 4 + jj) * 8 + si;
      const int c = slot ^ (rl & 7);
      const u16* asrc = (MODE == 0)
          ? (A + arow_src[jj] + k0 + c * 8)
          : (A + arow_src[jj] + (size_t)(k0 >> 6) * (NTOK * 64) + c * 8);
      gl_lds16(asrc, (char*)As + (wv * 4 + jj) * 1024);
      gl_lds16(Bt + (size_t)(bx * 128 + rl) * 512 + k0 + c * 8,
               (char*)Bs + (wv * 4 + jj) * 1024);
    }
    __syncthreads();
    #pragma unroll
    for (int kk = 0; kk < 2; ++kk) {
      bf16x8 af[4], bf[4];
      #pragma unroll
      for (int m = 0; m < 4; ++m) {
        const int row = wr * 64 + m * 16 + lr;
        af[m] = *(const bf16x8*)((const char*)As + row * 128 + (((kk * 4 + lk) ^ (row & 7)) << 4));
      }
      #pragma unroll
      for (int n = 0; n < 4; ++n) {
        const int row = wc * 64 + n * 16 + lr;
        bf[n] = *(const bf16x8*)((const char*)Bs + row * 128 + (((kk * 4 + lk) ^ (row & 7)) << 4));
      }
      #pragma unroll
      for (int m = 0; m < 4; ++m)
        #pragma unroll
        for (int n = 0; n < 4; ++n)
          acc[m][n] = __builtin_amdgcn_mfma_f32_16x16x32_bf16(af[m], bf[n], acc[m][n], 0, 0, 0);
    }
  }

  if (MODE == 0) {
    const int mat = (bx * 128) >> 9;
    u16* outp = (mat == 0) ? qb : (mat == 1) ? kb : vb;
    #pragma unroll
    for (int m = 0; m < 4; ++m) {
      #pragma unroll
      for (int r = 0; r < 4; ++r) {
        const int row = by * 128 + wr * 64 + m * 16 + lk * 4 + r;
        const int b = row / NTOK, t = row - b * NTOK;
        #pragma unroll
        for (int n = 0; n < 4; ++n) {
          const int col = bx * 128 + wc * 64 + n * 16 + lr;
          const int rem = col & 511, h = rem >> 6, d = rem & 63;
          outp[(((size_t)(b * NH_ + h)) * NTOK + t) * HD_ + d] = f2bfu(acc[m][n][r]);
        }
      }
    }
  } else {
    #pragma unroll
    for (int m = 0; m < 4; ++m) {
      #pragma unroll
      for (int r = 0; r < 4; ++r) {
        const int row = by * 128 + wr * 64 + m * 16 + lk * 4 + r;
        #pragma unroll
        for (int n = 0; n < 4; ++n) {
          const int col = bx * 128 + wc * 64 + n * 16 + lr;
          outf[(size_t)row * C_ + col] = acc[m][n][r] + bias[col];
        }
      }
    }
  }
}

// ---------------------------------------------------------------------------
// Bias precompute -> bf16, transposed layouts (bANT[h][t][a], bNAT[h][a][t])
// ---------------------------------------------------------------------------
__global__ void bias_kernel(const float* __restrict__ an, const float* __restrict__ na,
                            const float* __restrict__ ah, const float* __restrict__ aw,
                            const float* __restrict__ ha, const float* __restrict__ wa,
                            u16* __restrict__ bANT, u16* __restrict__ bNAT)
{
  const int blk = blockIdx.x;
  const int h = blk / AG_, a = blk - h * AG_;
  const int tid = threadIdx.x;
  if (tid >= NTOK) return;
  const int y = tid / H_, x = tid - y * H_;
  float cy = (y + 0.5f) * (7.0f / 18.0f) - 0.5f; cy = fminf(fmaxf(cy, 0.f), 6.f);
  float cx = (x + 0.5f) * (7.0f / 18.0f) - 0.5f; cx = fminf(fmaxf(cx, 0.f), 6.f);
  const int y0 = (int)floorf(cy); const float ty = cy - y0; const int y1 = min(y0 + 1, 6);
  const int x0 = (int)floorf(cx); const float tx = cx - x0; const int x1 = min(x0 + 1, 6);
  const float w00 = (1.f - ty) * (1.f - tx), w01 = (1.f - ty) * tx;
  const float w10 = ty * (1.f - tx), w11 = ty * tx;
  const float* anp = an + (size_t)blk * 49;
  const float* nap = na + (size_t)blk * 49;
  const float van = w00 * anp[y0*7+x0] + w01 * anp[y0*7+x1] + w10 * anp[y1*7+x0] + w11 * anp[y1*7+x1];
  const float vna = w00 * nap[y0*7+x0] + w01 * nap[y0*7+x1] + w10 * nap[y1*7+x0] + w11 * nap[y1*7+x1];
  bANT[((size_t)h * NTOK + tid) * AG_ + a] =
      f2bfu(van + ah[(size_t)blk * H_ + y] + aw[(size_t)blk * H_ + x]);
  bNAT[((size_t)h * AG_ + a) * NTOK + tid] =
      f2bfu(vna + ha[((size_t)h * H_ + y) * AG_ + a] + wa[((size_t)h * H_ + x) * AG_ + a]);
}

// ---------------------------------------------------------------------------
// Adaptive pool (unchanged, verified)
// ---------------------------------------------------------------------------
__global__ __launch_bounds__(512) void pool_kernel(const u16* __restrict__ qb, u16* __restrict__ agb)
{
  const int blk = blockIdx.x;
  const int b = blk / AG_, a = blk - b * AG_;
  const int o = a / 12, pc = a - o * 12;
  const int y0 = (3 * o) >> 1, x0 = (3 * pc) >> 1;
  const int c = threadIdx.x; const int h = c >> 6, d = c & 63;
  const size_t base = ((size_t)(b * NH_ + h)) * NTOK * HD_ + d;
  const int t00 = (y0 * H_ + x0) * HD_;
  const float v = bfu2f(qb[base + t00]) + bfu2f(qb[base + t00 + HD_])
                + bfu2f(qb[base + t00 + H_ * HD_]) + bfu2f(qb[base + t00 + H_ * HD_ + HD_]);
  agb[((size_t)(b * NH_ + h)) * AG_ * HD_ + a * HD_ + d] = f2bfu(0.25f * v);
}

// ---------------------------------------------------------------------------
// Depthwise 3x3 conv: aob[bh][t][d] = dwc(v). Runs AFTER stage1 (aob aliases
// kb), BEFORE stage2 (which RMW-adds attention).
// ---------------------------------------------------------------------------
__global__ __launch_bounds__(512) void dwc_kernel(
    const u16* __restrict__ vb, const float* __restrict__ dwc_w,
    const float* __restrict__ dwc_b, u16* __restrict__ aob)
{
  __shared__ __align__(16) u16 vL[NTOK * 64];
  const int hb = blockIdx.x, h = hb >> 7, b = hb & 127;
  const int bh = b * NH_ + h;
  const int tid = threadIdx.x;
  const bf16x8* vs = (const bf16x8*)(vb + (size_t)bh * NTOK * HD_);
  for (int idx = tid; idx < NTOK * 8; idx += 512)
    ((bf16x8*)vL)[idx] = vs[idx];
  const int d = tid & 63, tg = tid >> 6;
  float w9[9];
  #pragma unroll
  for (int j = 0; j < 9; ++j) w9[j] = dwc_w[(size_t)(h * 64 + d) * 9 + j];
  const float cb = dwc_b[h * 64 + d];
  __syncthreads();
  u16* aout = aob + (size_t)bh * NTOK * HD_;
  for (int t = tg; t < NTOK; t += 8) {
    const int y = t / H_, x = t - y * H_;
    float conv = cb;
    #pragma unroll
    for (int ky = 0; ky < 3; ++ky) {
      const int yy = y + ky - 1;
      if (yy < 0 || yy >= H_) continue;
      #pragma unroll
      for (int kx = 0; kx < 3; ++kx) {
        const int xc = x + kx - 1;
        if (xc < 0 || xc >= H_) continue;
        conv += w9[ky * 3 + kx] * bfu2f(vL[(yy * H_ + xc) * 64 + d]);
      }
    }
    aout[(size_t)t * HD_ + d] = f2bfu(conv);
  }
}

// ---------------------------------------------------------------------------
// Stage 1 (XCD-aligned heads: h = blockIdx & 7 -> all blocks sharing bANT[h]
// land on one XCD's L2).
// ---------------------------------------------------------------------------
__global__ __launch_bounds__(576) void stage1_k(
    const u16* __restrict__ kb, const u16* __restrict__ vb,
    const u16* __restrict__ agb, const u16* __restrict__ bANT,
    u16* __restrict__ avbT)
{
  __shared__ __align__(16) u16 vT[64 * 360];
  __shared__ __align__(16) u16 pW[9][16][40];
  const int hb = blockIdx.x, h = hb & 7, b = hb >> 3;   // XCD-aligned head
  const int bh = b * NH_ + h;
  const int tid = threadIdx.x;
  const int mt = tid >> 6, l = tid & 63, lr = l & 15, lk = l >> 4;

  // vT staging
  const u16* vsrc = vb + (size_t)bh * NTOK * HD_;
  for (int idx = tid; idx < 64 * 45; idx += 576) {
    const int d = idx & 63, c = idx >> 6;
    bf16x8 tv;
    #pragma unroll
    for (int j = 0; j < 8; ++j) {
      const int n = c * 8 + j;
      tv[j] = (n < NTOK) ? (short)vsrc[(size_t)n * HD_ + d] : (short)0;
    }
    *(bf16x8*)&vT[d * 360 + c * 8] = tv;
  }

  // QK
  const u16* aga = agb + ((size_t)bh * AG_ + mt * 16 + lr) * HD_ + lk * 8;
  const bf16x8 a0 = *(const bf16x8*)(aga);
  const bf16x8 a1 = *(const bf16x8*)(aga + 32);

  f32x4 acc[21];
  const u16* kbase = kb + (size_t)bh * NTOK * HD_ + lk * 8;
  __builtin_amdgcn_s_setprio(1);
  #pragma unroll
  for (int nt = 0; nt < 21; ++nt) {
    const bf16x8 b0 = *(const bf16x8*)(kbase + (size_t)(nt * 16 + lr) * HD_);
    const bf16x8 b1 = *(const bf16x8*)(kbase + (size_t)(nt * 16 + lr) * HD_ + 32);
    f32x4 c = {0.f, 0.f, 0.f, 0.f};
    c = __builtin_amdgcn_mfma_f32_16x16x32_bf16(a0, b0, c, 0, 0, 0);
    c = __builtin_amdgcn_mfma_f32_16x16x32_bf16(a1, b1, c, 0, 0, 0);
    acc[nt] = c;
  }
  __builtin_amdgcn_s_setprio(0);

  float mx[4] = {-1e30f, -1e30f, -1e30f, -1e30f};
  #pragma unroll
  for (int nt = 0; nt < 21; ++nt) {
    const int t = nt * 16 + lr;
    const bool valid = (nt < 20) || (lr < 4);
    ushort4 b4 = make_ushort4(0, 0, 0, 0);
    if (valid)
      b4 = *(const ushort4*)&bANT[((size_t)h * NTOK + t) * AG_ + mt * 16 + lk * 4];
    #pragma unroll
    for (int r = 0; r < 4; ++r) {
      float s = -1e30f;
      if (valid) s = acc[nt][r] * SCALE + bfu2f(((const u16*)&b4)[r]);
      acc[nt][r] = s;
      mx[r] = fmaxf(mx[r], s);
    }
  }
  #pragma unroll
  for (int r = 0; r < 4; ++r) {
    #pragma unroll
    for (int o = 1; o < 16; o <<= 1) mx[r] = fmaxf(mx[r], __shfl_xor(mx[r], o));
  }
  float sm[4] = {0.f, 0.f, 0.f, 0.f};
  #pragma unroll
  for (int nt = 0; nt < 21; ++nt) {
    #pragma unroll
    for (int r = 0; r < 4; ++r) {
      const float e = __expf(acc[nt][r] - mx[r]);
      acc[nt][r] = e;
      sm[r] += e;
    }
  }
  #pragma unroll
  for (int r = 0; r < 4; ++r) {
    #pragma unroll
    for (int o = 1; o < 16; o <<= 1) sm[r] += __shfl_xor(sm[r], o);
    sm[r] = 1.0f / sm[r];
  }

  __syncthreads();   // vT staged

  f32x4 ov[4];
  #pragma unroll
  for (int nt2 = 0; nt2 < 4; ++nt2) ov[nt2] = (f32x4){0.f, 0.f, 0.f, 0.f};
  for (int ks = 0; ks < 11; ++ks) {
    #pragma unroll
    for (int half = 0; half < 2; ++half) {
      const int nt = 2 * ks + half;
      #pragma unroll
      for (int r = 0; r < 4; ++r)
        pW[mt][lk * 4 + r][half * 16 + lr] = (nt < 21) ? f2bfu(acc[nt][r] * sm[r]) : (u16)0;
    }
    const bf16x8 pa = *(const bf16x8*)&pW[mt][lr][lk * 8];
    __builtin_amdgcn_s_setprio(1);
    #pragma unroll
    for (int nt2 = 0; nt2 < 4; ++nt2) {
      const bf16x8 vf = *(const bf16x8*)&vT[(nt2 * 16 + lr) * 360 + ks * 32 + lk * 8];
      ov[nt2] = __builtin_amdgcn_mfma_f32_16x16x32_bf16(pa, vf, ov[nt2], 0, 0, 0);
    }
    __builtin_amdgcn_s_setprio(0);
  }

  __syncthreads();   // PV reads of vT done

  u16* avTL = vT;    // [64][168] in dead vT region
  #pragma unroll
  for (int nt2 = 0; nt2 < 4; ++nt2) {
    ushort4 u;
    u.x = f2bfu(ov[nt2][0]); u.y = f2bfu(ov[nt2][1]);
    u.z = f2bfu(ov[nt2][2]); u.w = f2bfu(ov[nt2][3]);
    *(ushort4*)&avTL[(nt2 * 16 + lr) * 168 + mt * 16 + lk * 4] = u;
  }
  for (int idx = tid; idx < 128; idx += 576)
    *(bf16x8*)&avTL[(idx >> 1) * 168 + 144 + (idx & 1) * 8] = (bf16x8){0,0,0,0,0,0,0,0};

  __syncthreads();   // avT complete

  u16* dst = avbT + (size_t)bh * 64 * 160;
  for (int idx = tid; idx < 64 * 20; idx += 576) {
    const int d = idx / 20, c = idx - d * 20;
    *(bf16x8*)&dst[d * 160 + c * 8] = *(const bf16x8*)&avTL[d * 168 + c * 8];
  }
}

// ---------------------------------------------------------------------------
// Stage 2 (XCD-aligned heads + LDS out-bounce epilogue):
//  - h = blockIdx & 7 -> bNAT[h] shared in one XCD's L2.
//  - swapped PV frags bounced through per-wave oB[16][72] -> coalesced 32B/lane
//    RMW (read dwc, add, write) covering full 128B token lines.
// ---------------------------------------------------------------------------
__global__ __launch_bounds__(512, 6) void stage2_k(
    const u16* __restrict__ qb, const u16* __restrict__ agb,
    const u16* __restrict__ avbT, const u16* __restrict__ bNAT,
    u16* __restrict__ aob)
{
  __shared__ __align__(16) u16 avT[64 * 168];
  __shared__ __align__(16) u16 pW[8][16][40];
  __shared__ __align__(16) u16 oB[8][16][72];   // per-wave out bounce (144B rows)
  const int hb = blockIdx.x, h = hb & 7, b = hb >> 3;   // XCD-aligned head
  const int bh = b * NH_ + h;
  const int tid = threadIdx.x;
  const int wv = tid >> 6, l = tid & 63, lr = l & 15, lk = l >> 4;

  const u16* src = avbT + (size_t)bh * 64 * 160;
  for (int idx = tid; idx < 64 * 20; idx += 512) {
    const int d = idx / 20, c = idx - d * 20;
    *(bf16x8*)&avT[d * 168 + c * 8] = *(const bf16x8*)&src[d * 160 + c * 8];
  }
  __syncthreads();

  u16* aout = aob + (size_t)bh * NTOK * HD_;
  for (int mt2 = wv; mt2 < 21; mt2 += 8) {
    const int arow = min(mt2 * 16 + lr, NTOK - 1);
    const u16* qa = qb + ((size_t)bh * NTOK + arow) * HD_ + lk * 8;
    const bf16x8 qa0 = *(const bf16x8*)(qa);
    const bf16x8 qa1 = *(const bf16x8*)(qa + 32);

    f32x4 acc2[9];
    __builtin_amdgcn_s_setprio(1);
    #pragma unroll
    for (int nt = 0; nt < 9; ++nt) {
      const u16* bp = agb + ((size_t)bh * AG_ + nt * 16 + lr) * HD_ + lk * 8;
      f32x4 c = {0.f, 0.f, 0.f, 0.f};
      c = __builtin_amdgcn_mfma_f32_16x16x32_bf16(qa0, *(const bf16x8*)(bp), c, 0, 0, 0);
      c = __builtin_amdgcn_mfma_f32_16x16x32_bf16(qa1, *(const bf16x8*)(bp + 32), c, 0, 0, 0);
      acc2[nt] = c;
    }
    __builtin_amdgcn_s_setprio(0);

    float mx2[4] = {-1e30f, -1e30f, -1e30f, -1e30f};
    const int t0 = mt2 * 16 + lk * 4;
    #pragma unroll
    for (int nt = 0; nt < 9; ++nt) {
      const ushort4 b4 = *(const ushort4*)&bNAT[((size_t)h * AG_ + nt * 16 + lr) * NTOK + t0];
      #pragma unroll
      for (int r = 0; r < 4; ++r) {
        const float s = acc2[nt][r] * SCALE + bfu2f(((const u16*)&b4)[r]);
        acc2[nt][r] = s;
        mx2[r] = fmaxf(mx2[r], s);
      }
    }
    #pragma unroll
    for (int r = 0; r < 4; ++r) {
      #pragma unroll
      for (int o = 1; o < 16; o <<= 1) mx2[r] = fmaxf(mx2[r], __shfl_xor(mx2[r], o));
    }
    float sm2[4] = {0.f, 0.f, 0.f, 0.f};
    #pragma unroll
    for (int nt = 0; nt < 9; ++nt) {
      #pragma unroll
      for (int r = 0; r < 4; ++r) {
        const float e = __expf(acc2[nt][r] - mx2[r]);
        acc2[nt][r] = e;
        sm2[r] += e;
      }
    }
    #pragma unroll
    for (int r = 0; r < 4; ++r) {
      #pragma unroll
      for (int o = 1; o < 16; o <<= 1) sm2[r] += __shfl_xor(sm2[r], o);
      sm2[r] = 1.0f / sm2[r];
    }

    // swapped PV: D^T[d][t]
    f32x4 ov2[4];
    #pragma unroll
    for (int dt = 0; dt < 4; ++dt) ov2[dt] = (f32x4){0.f, 0.f, 0.f, 0.f};
    for (int ks = 0; ks < 5; ++ks) {
      #pragma unroll
      for (int half = 0; half < 2; ++half) {
        const int nt = 2 * ks + half;
        #pragma unroll
        for (int r = 0; r < 4; ++r)
          pW[wv][lk * 4 + r][half * 16 + lr] = (nt < 9) ? f2bfu(acc2[nt][r] * sm2[r]) : (u16)0;
      }
      const bf16x8 pa = *(const bf16x8*)&pW[wv][lr][lk * 8];
      __builtin_amdgcn_s_setprio(1);
      #pragma unroll
      for (int dt = 0; dt < 4; ++dt) {
        const bf16x8 vf = *(const bf16x8*)&avT[(dt * 16 + lr) * 168 + ks * 32 + lk * 8];
        ov2[dt] = __builtin_amdgcn_mfma_f32_16x16x32_bf16(vf, pa, ov2[dt], 0, 0, 0);
      }
      __builtin_amdgcn_s_setprio(0);
    }

    // epilogue: bounce through oB, then coalesced 32B/lane RMW (adds dwc)
    #pragma unroll
    for (int dt = 0; dt < 4; ++dt) {
      ushort4 u;
      u.x = f2bfu(ov2[dt][0]); u.y = f2bfu(ov2[dt][1]);
      u.z = f2bfu(ov2[dt][2]); u.w = f2bfu(ov2[dt][3]);
      *(ushort4*)&oB[wv][lr][dt * 16 + lk * 4] = u;   // lane owns token lr
    }
    // wave-synchronous LDS RAW (same wave; ds ops complete in order via lgkmcnt)
    const int tloc = l >> 2, part = l & 3;
    if (mt2 * 16 + tloc < NTOK) {
      u16* gp = &aout[(size_t)(mt2 * 16 + tloc) * HD_ + part * 16];
      const u16* lp = &oB[wv][tloc][part * 16];
      const bf16x8 g0 = *(const bf16x8*)(gp);
      const bf16x8 g1 = *(const bf16x8*)(gp + 8);
      const bf16x8 l0 = *(const bf16x8*)(lp);
      const bf16x8 l1 = *(const bf16x8*)(lp + 8);
      bf16x8 o0, o1;
      #pragma unroll
      for (int j = 0; j < 8; ++j) {
        o0[j] = (short)f2bfu(bfu2f((u16)g0[j]) + bfu2f((u16)l0[j]));
        o1[j] = (short)f2bfu(bfu2f((u16)g1[j]) + bfu2f((u16)l1[j]));
      }
      *(bf16x8*)(gp) = o0;
      *(bf16x8*)(gp + 8) = o1;
    }
  }
}

extern "C" void kernel_launch(void* const* d_in, const int* in_sizes, int n_in,
                              void* d_out, int out_size, void* d_ws, size_t ws_size,
                              hipStream_t stream)
{
  (void)in_sizes; (void)n_in; (void)out_size;
  const float* x      = (const float*)d_in[0];
  const float* qkv_w  = (const float*)d_in[1];
  const float* proj_w = (const float*)d_in[2];
  const float* proj_b = (const float*)d_in[3];
  const float* dwc_w  = (const float*)d_in[4];
  const float* dwc_b  = (const float*)d_in[5];
  const float* an     = (const float*)d_in[6];
  const float* na     = (const float*)d_in[7];
  const float* ah     = (const float*)d_in[8];
  const float* aw     = (const float*)d_in[9];
  const float* ha     = (const float*)d_in[10];
  const float* wa     = (const float*)d_in[11];

  char* ws = (char*)d_ws;
  const size_t QB   = (size_t)B_ * NH_ * NTOK * HD_ * 2;   // 42,467,328 (== xp bytes)
  const size_t AGB  = (size_t)B_ * NH_ * AG_  * HD_ * 2;   // 18,874,368
  const size_t AVTB = (size_t)B_ * NH_ * 64 * 160 * 2;     // 20,971,520
  const size_t BB   = (size_t)NH_ * AG_ * NTOK * 2 + 64;   //    746,560
  const size_t WQ   = (size_t)1536 * 512 * 2;              //  1,572,864
  const size_t WP   = (size_t)512 * 512 * 2;               //    524,288
  u16* qb    = (u16*)(ws);
  u16* kb    = (u16*)(ws + QB);
  u16* vb    = (u16*)(ws + 2 * QB);
  u16* xp    = (u16*)(ws + 3 * QB);                        // dead after GEMM<0>
  u16* agb   = (u16*)(ws + 3 * QB);                        // overlays xp
  u16* avbT  = (u16*)(ws + 3 * QB + AGB);                  // overlays xp
  u16* bANT  = (u16*)(ws + 3 * QB + AGB + AVTB);           // overlays xp tail (40.6<42.5MB)
  u16* wqkvT = (u16*)(ws + 4 * QB);
  u16* wprojT= (u16*)(ws + 4 * QB + WQ);
  u16* bNAT  = (u16*)(ws + 4 * QB + WQ + WP);
  u16* aob   = kb;                                         // [bh][t][d]; block-exclusive
  if (ws_size < 4 * QB + WQ + WP + BB) return;

  conv_x   <<<dim3(B_ * NTOK * 64 / 256), dim3(256), 0, stream>>>(x, xp);
  tconv    <<<dim3(8, 24), dim3(256), 0, stream>>>(qkv_w, wqkvT, 1536);
  tconv    <<<dim3(8, 8),  dim3(256), 0, stream>>>(proj_w, wprojT, 512);
  mfma_gemm<0><<<dim3(12, 324), dim3(256), 0, stream>>>(xp, wqkvT, qb, kb, vb, nullptr, nullptr);
  pool_kernel<<<dim3(B_ * AG_),  dim3(512), 0, stream>>>(qb, agb);
  bias_kernel<<<dim3(NH_ * AG_), dim3(324), 0, stream>>>(an, na, ah, aw, ha, wa, bANT, bNAT);
  stage1_k <<<dim3(NH_ * B_), dim3(576), 0, stream>>>(kb, vb, agb, bANT, avbT);
  dwc_kernel<<<dim3(NH_ * B_), dim3(512), 0, stream>>>(vb, dwc_w, dwc_b, aob);
  stage2_k <<<dim3(NH_ * B_), dim3(512), 0, stream>>>(qb, agb, avbT, bNAT, aob);
  mfma_gemm<1><<<dim3(4, 320), dim3(256), 0, stream>>>(aob, wprojT, nullptr, nullptr, nullptr, proj_b, (float*)d_out);
}